// Round 8
// baseline (9207.358 us; speedup 1.0000x reference)
//
#include <hip/hip_runtime.h>
#include <hip/hip_bf16.h>

// ---------------------------------------------------------------------------
// Net_49976239456390 — Round 8: hoist bf16 splits out of GEMM2's K-loop.
//   - gemm1 epilogue writes h1 as 3 pre-split bf16 planes (no fp32 h1)
//   - w2split kernel pre-splits W2 into 3 transposed planes [n][k] (once)
//   - gemm2_pre: staging + MFMA only (reg-staged prefetch, LDT=40 pad)
//   MFMA order identical to round 7 -> h2 bit-identical -> absmax must stay
//   6.103516e-05 (built-in regression check).
// GEMM3 (2-term in-kernel split), kwinner, GEMM4 unchanged.
// ---------------------------------------------------------------------------

#define BDIM 8192
#define IDIM 4096
#define DDIM 8192
#define XDIM 784
#define KNEUR 512
#define KSTR  16

typedef __attribute__((ext_vector_type(8))) short bf16x8;
typedef __attribute__((ext_vector_type(4))) float f32x4;

#define LDT 40                    // padded LDS row: 40 shorts = 80 B
#define BPL 33554432ull           // B plane stride: 8192*4096 shorts

// identifier-named kernel: grid-stride fp32 fill (sentinel / error codes)
__global__ void Net_49976239456390_kernel(float* out, unsigned long long n, float v)
{
    unsigned long long i = (unsigned long long)blockIdx.x * blockDim.x + threadIdx.x;
    unsigned long long step = (unsigned long long)gridDim.x * blockDim.x;
    for (; i < n; i += step) out[i] = v;
}

// ---- exact bf16 splits ------------------------------------------------------
__device__ __forceinline__ void split3(float f, short& s0, short& s1, short& s2)
{
    __hip_bfloat16 b0 = __float2bfloat16(f);
    float r1 = f - __bfloat162float(b0);
    __hip_bfloat16 b1 = __float2bfloat16(r1);
    float r2 = r1 - __bfloat162float(b1);
    __hip_bfloat16 b2 = __float2bfloat16(r2);
    s0 = *(short*)&b0; s1 = *(short*)&b1; s2 = *(short*)&b2;
}

__device__ __forceinline__ void split2(float f, short& s0, short& s1)
{
    __hip_bfloat16 b0 = __float2bfloat16(f);
    float r1 = f - __bfloat162float(b0);
    __hip_bfloat16 b1 = __float2bfloat16(r1);
    s0 = *(short*)&b0; s1 = *(short*)&b1;
}

// ---- fp32 GEMM: C = relu(A @ B + bias) (GEMM4; N guarded) -------------------
__global__ __launch_bounds__(256)
void gemm_relu(const float* A, const float* B, const float* bias, float* C,
               int N, int K)
{
    __shared__ float as[8][128];
    __shared__ float bs[8][128];

    const int tid = threadIdx.x;
    const int bm = blockIdx.y * 128;
    const int bn = blockIdx.x * 128;
    const int tx = tid & 15, ty = tid >> 4;
    const int r0 = ty * 4, c0 = tx * 4;
    const int a_m = tid >> 1, a_k = (tid & 1) * 4;
    const int b_k = tid >> 5, b_n = (tid & 31) * 4;

    const float* Ap = A + (size_t)(bm + a_m) * K + a_k;
    const float* Bp = B + (size_t)b_k * N + (bn + b_n);
    const bool bok = (bn + b_n + 3 < N);

    float acc[8][8];
#pragma unroll
    for (int i = 0; i < 8; ++i)
#pragma unroll
        for (int j = 0; j < 8; ++j) acc[i][j] = 0.f;

    for (int k0 = 0; k0 < K; k0 += 8) {
        float4 av = *(const float4*)(Ap + k0);
        float4 bv = make_float4(0.f, 0.f, 0.f, 0.f);
        if (bok) bv = *(const float4*)(Bp + (size_t)k0 * N);
        __syncthreads();
        as[a_k + 0][a_m] = av.x;
        as[a_k + 1][a_m] = av.y;
        as[a_k + 2][a_m] = av.z;
        as[a_k + 3][a_m] = av.w;
        *(float4*)&bs[b_k][b_n] = bv;
        __syncthreads();
#pragma unroll
        for (int k = 0; k < 8; ++k) {
            float4 a0 = *(const float4*)&as[k][r0];
            float4 a1 = *(const float4*)&as[k][r0 + 64];
            float4 b0 = *(const float4*)&bs[k][c0];
            float4 b1 = *(const float4*)&bs[k][c0 + 64];
            float aa[8] = {a0.x, a0.y, a0.z, a0.w, a1.x, a1.y, a1.z, a1.w};
            float bb[8] = {b0.x, b0.y, b0.z, b0.w, b1.x, b1.y, b1.z, b1.w};
#pragma unroll
            for (int i = 0; i < 8; ++i)
#pragma unroll
                for (int j = 0; j < 8; ++j)
                    acc[i][j] = fmaf(aa[i], bb[j], acc[i][j]);
        }
    }

#pragma unroll
    for (int i = 0; i < 8; ++i) {
        const int rr = bm + r0 + ((i >> 2) << 6) + (i & 3);
        float* op = C + (size_t)rr * N;
#pragma unroll
        for (int j = 0; j < 8; ++j) {
            int cc = bn + c0 + ((j >> 2) << 6) + (j & 3);
            if (cc < N)
                op[cc] = fmaxf(acc[i][j] + bias[cc], 0.f);
        }
    }
}

// ---- GEMM1: Aplanes = split3(relu(x @ W1 + b1)) -----------------------------
// Same fp32 core as gemm_relu (N=IDIM fixed, no guard); epilogue writes 3
// bf16 planes [M][IDIM] instead of fp32.
__global__ __launch_bounds__(256)
void gemm1_split(const float* A, const float* B, const float* bias,
                 short* Ap0, size_t strideA, int K)
{
    __shared__ float as[8][128];
    __shared__ float bs[8][128];

    const int tid = threadIdx.x;
    const int bm = blockIdx.y * 128;
    const int bn = blockIdx.x * 128;
    const int tx = tid & 15, ty = tid >> 4;
    const int r0 = ty * 4, c0 = tx * 4;
    const int a_m = tid >> 1, a_k = (tid & 1) * 4;
    const int b_k = tid >> 5, b_n = (tid & 31) * 4;

    const float* Apr = A + (size_t)(bm + a_m) * K + a_k;
    const float* Bpr = B + (size_t)b_k * IDIM + (bn + b_n);

    float acc[8][8];
#pragma unroll
    for (int i = 0; i < 8; ++i)
#pragma unroll
        for (int j = 0; j < 8; ++j) acc[i][j] = 0.f;

    for (int k0 = 0; k0 < K; k0 += 8) {
        float4 av = *(const float4*)(Apr + k0);
        float4 bv = *(const float4*)(Bpr + (size_t)k0 * IDIM);
        __syncthreads();
        as[a_k + 0][a_m] = av.x;
        as[a_k + 1][a_m] = av.y;
        as[a_k + 2][a_m] = av.z;
        as[a_k + 3][a_m] = av.w;
        *(float4*)&bs[b_k][b_n] = bv;
        __syncthreads();
#pragma unroll
        for (int k = 0; k < 8; ++k) {
            float4 a0 = *(const float4*)&as[k][r0];
            float4 a1 = *(const float4*)&as[k][r0 + 64];
            float4 b0 = *(const float4*)&bs[k][c0];
            float4 b1 = *(const float4*)&bs[k][c0 + 64];
            float aa[8] = {a0.x, a0.y, a0.z, a0.w, a1.x, a1.y, a1.z, a1.w};
            float bb[8] = {b0.x, b0.y, b0.z, b0.w, b1.x, b1.y, b1.z, b1.w};
#pragma unroll
            for (int i = 0; i < 8; ++i)
#pragma unroll
                for (int j = 0; j < 8; ++j)
                    acc[i][j] = fmaf(aa[i], bb[j], acc[i][j]);
        }
    }

    short* Ap1 = Ap0 + strideA;
    short* Ap2 = Ap1 + strideA;
#pragma unroll
    for (int i = 0; i < 8; ++i) {
        const int rr = bm + r0 + ((i >> 2) << 6) + (i & 3);
        size_t rowoff = (size_t)rr * IDIM;
#pragma unroll
        for (int jj = 0; jj < 2; ++jj) {
            int cc = bn + c0 + jj * 64;
            short s0[4], s1[4], s2[4];
#pragma unroll
            for (int e = 0; e < 4; ++e) {
                float v = fmaxf(acc[i][jj * 4 + e] + bias[cc + e], 0.f);
                split3(v, s0[e], s1[e], s2[e]);
            }
            *(short4*)(Ap0 + rowoff + cc) = make_short4(s0[0], s0[1], s0[2], s0[3]);
            *(short4*)(Ap1 + rowoff + cc) = make_short4(s1[0], s1[1], s1[2], s1[3]);
            *(short4*)(Ap2 + rowoff + cc) = make_short4(s2[0], s2[1], s2[2], s2[3]);
        }
    }
}

// ---- W2 -> 3 transposed bf16 planes [n][k] ---------------------------------
__global__ __launch_bounds__(256)
void w2split(const float* __restrict__ W2, short* __restrict__ Bp)
{
    __shared__ float t[64][65];
    const int n0 = blockIdx.x * 64, k0 = blockIdx.y * 64;
    const int tid = threadIdx.x;

#pragma unroll
    for (int p = 0; p < 4; ++p) {
        int idx = p * 256 + tid;
        int kr = idx >> 4, nc = (idx & 15) * 4;
        float4 v = *(const float4*)(W2 + (size_t)(k0 + kr) * DDIM + n0 + nc);
        t[kr][nc + 0] = v.x; t[kr][nc + 1] = v.y;
        t[kr][nc + 2] = v.z; t[kr][nc + 3] = v.w;
    }
    __syncthreads();
#pragma unroll
    for (int p = 0; p < 4; ++p) {
        int idx = p * 256 + tid;
        int nr = idx >> 4, kc = (idx & 15) * 4;
        short s0[4], s1[4], s2[4];
#pragma unroll
        for (int e = 0; e < 4; ++e)
            split3(t[kc + e][nr], s0[e], s1[e], s2[e]);
        size_t off = (size_t)(n0 + nr) * IDIM + k0 + kc;
        *(short4*)(Bp + off)           = make_short4(s0[0], s0[1], s0[2], s0[3]);
        *(short4*)(Bp + BPL + off)     = make_short4(s1[0], s1[1], s1[2], s1[3]);
        *(short4*)(Bp + 2 * BPL + off) = make_short4(s2[0], s2[1], s2[2], s2[3]);
    }
}

// ---- GEMM2: h2 = relu(Aplanes @ BplanesT + b2), pure MFMA loop --------------
// Aplanes: 3x [M][IDIM] bf16; Bplanes: 3x [DDIM][IDIM] bf16 (transposed).
// 128x128 tile, BK=32, 256 thr (2x2 waves of 64x64), reg-staged prefetch.
// MFMA order identical to round 7 (bit-identical h2).
__global__ __launch_bounds__(256, 2)
void gemm2_pre(const short* __restrict__ Ap, const short* __restrict__ Bp,
               const float* __restrict__ bias, float* __restrict__ C,
               size_t strideA)
{
    __shared__ short lds[6 * 128 * LDT];   // 61440 B: planes A0,A1,A2,B0,B1,B2

    const int tid = threadIdx.x;
    const int lane = tid & 63;
    const int wid = tid >> 6;
    const int wr = (wid >> 1) * 64;
    const int wc = (wid & 1) * 64;
    const int l15 = lane & 15;
    const int lk8 = (lane >> 4) * 8;
    const int bm = blockIdx.y * 128;
    const int bn = blockIdx.x * 128;

    // staging decomposition: 6 planes x 128 rows x 32k = 12 chunks of 16B/thr
    const short* srcb[12];
    int ldso[12];
#pragma unroll
    for (int ch = 0; ch < 12; ++ch) {
        int g = ch * 256 + tid;
        int pl = g >> 9;               // 0..5
        int rr = (g >> 2) & 127;
        int c8 = (g & 3) * 8;
        srcb[ch] = (pl < 3)
            ? Ap + (size_t)pl * strideA + (size_t)(bm + rr) * IDIM + c8
            : Bp + (size_t)(pl - 3) * BPL + (size_t)(bn + rr) * IDIM + c8;
        ldso[ch] = pl * (128 * LDT) + rr * LDT + c8;
    }

    f32x4 accM[4][4];
    f32x4 accR[4][4];
#pragma unroll
    for (int i = 0; i < 4; ++i)
#pragma unroll
        for (int j = 0; j < 4; ++j) {
            accM[i][j] = (f32x4){0.f, 0.f, 0.f, 0.f};
            accR[i][j] = (f32x4){0.f, 0.f, 0.f, 0.f};
        }

    bf16x8 st[12];
#pragma unroll
    for (int ch = 0; ch < 12; ++ch)
        st[ch] = *(const bf16x8*)(srcb[ch]);

    for (int k0 = 0; k0 < IDIM; k0 += 32) {
        __syncthreads();               // prior iter's frag reads done
#pragma unroll
        for (int ch = 0; ch < 12; ++ch)
            *(bf16x8*)&lds[ldso[ch]] = st[ch];
        __syncthreads();               // tiles ready

        int kn = k0 + 32;
        if (kn < IDIM) {
#pragma unroll
            for (int ch = 0; ch < 12; ++ch)
                st[ch] = *(const bf16x8*)(srcb[ch] + kn);   // in flight over MFMA
        }

#pragma unroll
        for (int q = 0; q < 3; ++q) {
            bf16x8 bf[4];
#pragma unroll
            for (int ni = 0; ni < 4; ++ni)
                bf[ni] = *(const bf16x8*)&lds[(3 + q) * (128 * LDT) + (wc + ni * 16 + l15) * LDT + lk8];
#pragma unroll
            for (int p = 0; p <= 2 - q; ++p) {
                bf16x8 af[4];
#pragma unroll
                for (int mi = 0; mi < 4; ++mi)
                    af[mi] = *(const bf16x8*)&lds[p * (128 * LDT) + (wr + mi * 16 + l15) * LDT + lk8];
#pragma unroll
                for (int mi = 0; mi < 4; ++mi)
#pragma unroll
                    for (int ni = 0; ni < 4; ++ni) {
                        if (p == 0 && q == 0)
                            accM[mi][ni] = __builtin_amdgcn_mfma_f32_16x16x32_bf16(
                                af[mi], bf[ni], accM[mi][ni], 0, 0, 0);
                        else
                            accR[mi][ni] = __builtin_amdgcn_mfma_f32_16x16x32_bf16(
                                af[mi], bf[ni], accR[mi][ni], 0, 0, 0);
                    }
            }
        }
    }

    const int rsub = (lane >> 4) * 4;
#pragma unroll
    for (int mi = 0; mi < 4; ++mi) {
        int row0 = bm + wr + mi * 16 + rsub;
#pragma unroll
        for (int ni = 0; ni < 4; ++ni) {
            int col = bn + wc + ni * 16 + l15;
            float bb = bias[col];
#pragma unroll
            for (int r = 0; r < 4; ++r) {
                float s = accR[mi][ni][r] + accM[mi][ni][r];
                C[(size_t)(row0 + r) * DDIM + col] = fmaxf(s + bb, 0.f);
            }
        }
    }
}

// ---- GEMM3: h3 = relu(flat @ W3 + b3), 2-term in-kernel split (round 7) ----
__global__ __launch_bounds__(256, 2)
void gemm3_split(const float* __restrict__ A, const float* __restrict__ B,
                 const float* __restrict__ bias, float* __restrict__ C)
{
    __shared__ short as[2][128 * LDT];
    __shared__ short bs[2][128 * LDT];
    __shared__ float bsrc[32 * 128];

    const int tid = threadIdx.x;
    const int lane = tid & 63;
    const int wid = tid >> 6;
    const int wr = (wid >> 1) * 64;
    const int wc = (wid & 1) * 64;
    const int l15 = lane & 15;
    const int lk8 = (lane >> 4) * 8;
    const int bm = blockIdx.y * 128;
    const int bn = blockIdx.x * 128;

    const int tn = tid & 127;
    const int tkh = (tid >> 7) * 16;

    f32x4 accM[4][4];
    f32x4 accR[4][4];
#pragma unroll
    for (int i = 0; i < 4; ++i)
#pragma unroll
        for (int j = 0; j < 4; ++j) {
            accM[i][j] = (f32x4){0.f, 0.f, 0.f, 0.f};
            accR[i][j] = (f32x4){0.f, 0.f, 0.f, 0.f};
        }

    for (int k0 = 0; k0 < DDIM; k0 += 32) {
        __syncthreads();

#pragma unroll
        for (int pass = 0; pass < 4; ++pass) {
            int idx = pass * 256 + tid;
            int m = idx >> 3;
            int kf = (idx & 7) << 2;
            float4 v = *(const float4*)(A + (size_t)(bm + m) * DDIM + k0 + kf);
            short s0[4], s1[4];
            split2(v.x, s0[0], s1[0]);
            split2(v.y, s0[1], s1[1]);
            split2(v.z, s0[2], s1[2]);
            split2(v.w, s0[3], s1[3]);
            int off = m * LDT + kf;
            *(short4*)&as[0][off] = make_short4(s0[0], s0[1], s0[2], s0[3]);
            *(short4*)&as[1][off] = make_short4(s1[0], s1[1], s1[2], s1[3]);
        }
#pragma unroll
        for (int pass = 0; pass < 4; ++pass) {
            int idx = pass * 256 + tid;
            int k = idx >> 5;
            int nf = (idx & 31) << 2;
            float4 v = *(const float4*)(B + (size_t)(k0 + k) * IDIM + bn + nf);
            *(float4*)&bsrc[k * 128 + nf] = v;
        }
        __syncthreads();

#pragma unroll
        for (int q = 0; q < 4; ++q) {
            int kq = tkh + q * 4;
            short s0[4], s1[4];
#pragma unroll
            for (int e = 0; e < 4; ++e) {
                float f = bsrc[(kq + e) * 128 + tn];
                split2(f, s0[e], s1[e]);
            }
            int off = tn * LDT + kq;
            *(short4*)&bs[0][off] = make_short4(s0[0], s0[1], s0[2], s0[3]);
            *(short4*)&bs[1][off] = make_short4(s1[0], s1[1], s1[2], s1[3]);
        }
        __syncthreads();

        bf16x8 af[2][4];
#pragma unroll
        for (int p = 0; p < 2; ++p)
#pragma unroll
            for (int mi = 0; mi < 4; ++mi)
                af[p][mi] = *(const bf16x8*)&as[p][(wr + mi * 16 + l15) * LDT + lk8];

#pragma unroll
        for (int q = 0; q < 2; ++q) {
            bf16x8 bf[4];
#pragma unroll
            for (int ni = 0; ni < 4; ++ni)
                bf[ni] = *(const bf16x8*)&bs[q][(wc + ni * 16 + l15) * LDT + lk8];
#pragma unroll
            for (int p = 0; p < 2; ++p) {
                if (p + q > 1) continue;
                if (p == 0 && q == 0) {
#pragma unroll
                    for (int mi = 0; mi < 4; ++mi)
#pragma unroll
                        for (int ni = 0; ni < 4; ++ni)
                            accM[mi][ni] = __builtin_amdgcn_mfma_f32_16x16x32_bf16(
                                af[0][mi], bf[ni], accM[mi][ni], 0, 0, 0);
                } else {
#pragma unroll
                    for (int mi = 0; mi < 4; ++mi)
#pragma unroll
                        for (int ni = 0; ni < 4; ++ni)
                            accR[mi][ni] = __builtin_amdgcn_mfma_f32_16x16x32_bf16(
                                af[p][mi], bf[ni], accR[mi][ni], 0, 0, 0);
                }
            }
        }
    }

    const int rsub = (lane >> 4) * 4;
#pragma unroll
    for (int mi = 0; mi < 4; ++mi) {
        int row0 = bm + wr + mi * 16 + rsub;
#pragma unroll
        for (int ni = 0; ni < 4; ++ni) {
            int col = bn + wc + ni * 16 + l15;
            float bb = bias[col];
#pragma unroll
            for (int r = 0; r < 4; ++r) {
                float s = accR[mi][ni][r] + accM[mi][ni][r];
                C[(size_t)(row0 + r) * IDIM + col] = fmaxf(s + bb, 0.f);
            }
        }
    }
}

// ---- k-winner (exact top-512, radix on fp32 bits, jax leftmost ties) -------
__global__ __launch_bounds__(256)
void kwinner_stripes(float* h2, const float* bscores)
{
    const int row = blockIdx.x;
    const int tid = threadIdx.x;
    float* rowp = h2 + (size_t)row * DDIM;

    __shared__ float  mv[DDIM];
    __shared__ int    ired[256];
    __shared__ double dred[256];
    __shared__ int    warr[4];
    __shared__ double ssum[128];
    __shared__ float  smk[128];

#pragma unroll
    for (int i = 0; i < 32; ++i) {
        int j = tid + i * 256;
        mv[j] = expf(0.0f - bscores[j]) * rowp[j];   // BETA=1, GAMMA=0
    }
    __syncthreads();

    unsigned t = 0;
    for (int bit = 30; bit >= 0; --bit) {
        unsigned cand = t | (1u << bit);
        int cnt = 0;
#pragma unroll
        for (int i = 0; i < 32; ++i)
            cnt += (__float_as_uint(mv[tid + i * 256]) >= cand) ? 1 : 0;
        for (int off = 32; off; off >>= 1) cnt += __shfl_down(cnt, off);
        if ((tid & 63) == 0) warr[tid >> 6] = cnt;
        __syncthreads();
        int tot = warr[0] + warr[1] + warr[2] + warr[3];
        __syncthreads();
        if (tot >= KNEUR) t = cand;
    }
    {
        int cnt = 0;
#pragma unroll
        for (int i = 0; i < 32; ++i)
            cnt += (__float_as_uint(mv[tid + i * 256]) > t) ? 1 : 0;
        for (int off = 32; off; off >>= 1) cnt += __shfl_down(cnt, off);
        if ((tid & 63) == 0) warr[tid >> 6] = cnt;
        __syncthreads();
    }
    const int need_eq = KNEUR - (warr[0] + warr[1] + warr[2] + warr[3]);
    __syncthreads();

    const int base = tid * 32;
    int myeq = 0;
#pragma unroll
    for (int i = 0; i < 32; ++i)
        myeq += (__float_as_uint(mv[base + i]) == t) ? 1 : 0;
    int val = myeq;
    ired[tid] = val;
    __syncthreads();
    for (int s = 1; s < 256; s <<= 1) {
        int add = (tid >= s) ? ired[tid - s] : 0;
        __syncthreads();
        val += add;
        ired[tid] = val;
        __syncthreads();
    }
    const int before = val - myeq;

    double partial = 0.0;
    int eqseen = 0;
#pragma unroll
    for (int i = 0; i < 32; ++i) {
        int j = base + i;
        float m = mv[j];
        unsigned u = __float_as_uint(m);
        bool sel = (u > t) || (u == t && (before + eqseen) < need_eq);
        if (u == t) ++eqseen;
        float code = sel ? m * rowp[j] : 0.f;
        mv[j] = code;
        partial += (double)code;
    }
    dred[tid] = partial;
    __syncthreads();
    if (tid < 128) ssum[tid] = dred[2 * tid] + dred[2 * tid + 1];
    __syncthreads();

    if (tid < 128) {
        double v = ssum[tid];
        int rank = 0;
        for (int j = 0; j < 128; ++j) {
            double w = ssum[j];
            rank += (w > v) ? 1 : 0;
            rank += (w == v && j < tid) ? 1 : 0;
        }
        smk[tid] = (rank < KSTR) ? 1.f : 0.f;
    }
    __syncthreads();

#pragma unroll
    for (int i = 0; i < 32; ++i) {
        int j = tid + i * 256;
        rowp[j] = mv[j] * smk[j >> 6];
    }
}

// ---------------------------------------------------------------------------
extern "C" void kernel_launch(void* const* d_in, const int* in_sizes, int n_in,
                              void* d_out, int out_size, void* d_ws, size_t ws_size,
                              hipStream_t stream)
{
    float* out = (float*)d_out;
    const unsigned long long on = (unsigned long long)out_size;

    if (n_in != 10) {
        Net_49976239456390_kernel<<<1024, 256, 0, stream>>>(out, on, 55.f);
        return;
    }
    if (in_sizes[0] != BDIM * XDIM || in_sizes[3] != IDIM * DDIM || in_sizes[9] != DDIM) {
        Net_49976239456390_kernel<<<1024, 256, 0, stream>>>(out, on, 66.f);
        return;
    }

    // ws layout: [W2T planes: 3*DDIM*IDIM*2 B][Aplanes: R*IDIM*6 B][h2: R*DDIM*4 B]
    // h3 (R*IDIM*4 B) aliases the Aplanes region (6 B/elem >= 4 B/elem).
    const size_t fixed = 3ull * DDIM * IDIM * 2;      // 201326592
    const size_t per_row = (size_t)IDIM * 6 + (size_t)DDIM * 4;   // 57344
    int R = 0;
    for (int cand = BDIM; cand >= 128; cand >>= 1)
        if (fixed + (size_t)cand * per_row <= ws_size) { R = cand; break; }
    if (R == 0) {
        Net_49976239456390_kernel<<<1024, 256, 0, stream>>>(out, on, 99.f);
        return;
    }

    Net_49976239456390_kernel<<<1024, 256, 0, stream>>>(out, on, 7.f);

    const float* x   = (const float*)d_in[0];
    const float* W1  = (const float*)d_in[1];
    const float* b1  = (const float*)d_in[2];
    const float* W2  = (const float*)d_in[3];
    const float* b2  = (const float*)d_in[4];
    const float* W3  = (const float*)d_in[5];
    const float* b3  = (const float*)d_in[6];
    const float* W4  = (const float*)d_in[7];
    const float* b4  = (const float*)d_in[8];
    const float* bsc = (const float*)d_in[9];

    short* bplanes = (short*)d_ws;
    short* aplanes = (short*)((char*)d_ws + fixed);
    const size_t strideA = (size_t)R * IDIM;
    float* h2 = (float*)((char*)d_ws + fixed + strideA * 6);
    float* h3 = (float*)aplanes;                      // alias (post-gemm2)

    dim3 blk(256);

    // W2 -> 3 transposed bf16 planes (once per launch)
    w2split<<<dim3(DDIM / 64, IDIM / 64), blk, 0, stream>>>(W2, bplanes);

    for (int cs = 0; cs < BDIM; cs += R) {
        const float* xC = x + (size_t)cs * XDIM;
        float* outC = out + (size_t)cs * XDIM;

        gemm1_split<<<dim3(IDIM / 128, R / 128), blk, 0, stream>>>(
            xC, W1, b1, aplanes, strideA, XDIM);
        gemm2_pre<<<dim3(DDIM / 128, R / 128), blk, 0, stream>>>(
            aplanes, bplanes, b2, h2, strideA);
        kwinner_stripes<<<dim3(R), blk, 0, stream>>>(h2, bsc);
        gemm3_split<<<dim3(IDIM / 128, R / 128), blk, 0, stream>>>(
            h2, W3, b3, h3);
        gemm_relu<<<dim3((XDIM + 127) / 128, R / 128), blk, 0, stream>>>(
            h3, W4, b4, outC, XDIM, IDIM);
    }
}

// Round 9
// 8999.966 us; speedup vs baseline: 1.0230x; 1.0230x over previous
//
#include <hip/hip_runtime.h>
#include <hip/hip_bf16.h>

// ---------------------------------------------------------------------------
// Net_49976239456390 — Round 9: A-side pre-split only (round-8 post-mortem:
// pre-splitting B inflated LLC working set 128->201 MB -> HBM-bound).
//   - gemm1 epilogue -> h1 as 3 bf16 planes (streamed once; no reuse lost)
//   - kwinner -> flat as 2 bf16 planes (same bytes as fp32; split hoisted)
//   - gemm2_mix / gemm3_mix: A from planes (no VALU), B fp32 LLC-resident
//     with in-kernel split (round-7 path)
//   MFMA order/operands bit-identical to round 7 -> absmax must be exactly
//   6.103516e-05.
// ---------------------------------------------------------------------------

#define BDIM 8192
#define IDIM 4096
#define DDIM 8192
#define XDIM 784
#define KNEUR 512
#define KSTR  16

typedef __attribute__((ext_vector_type(8))) short bf16x8;
typedef __attribute__((ext_vector_type(4))) float f32x4;

#define LDT 40   // padded LDS row: 40 shorts = 80 B

// identifier-named kernel: grid-stride fp32 fill (sentinel / error codes)
__global__ void Net_49976239456390_kernel(float* out, unsigned long long n, float v)
{
    unsigned long long i = (unsigned long long)blockIdx.x * blockDim.x + threadIdx.x;
    unsigned long long step = (unsigned long long)gridDim.x * blockDim.x;
    for (; i < n; i += step) out[i] = v;
}

// ---- exact bf16 splits ------------------------------------------------------
__device__ __forceinline__ void split3(float f, short& s0, short& s1, short& s2)
{
    __hip_bfloat16 b0 = __float2bfloat16(f);
    float r1 = f - __bfloat162float(b0);
    __hip_bfloat16 b1 = __float2bfloat16(r1);
    float r2 = r1 - __bfloat162float(b1);
    __hip_bfloat16 b2 = __float2bfloat16(r2);
    s0 = *(short*)&b0; s1 = *(short*)&b1; s2 = *(short*)&b2;
}

__device__ __forceinline__ void split2(float f, short& s0, short& s1)
{
    __hip_bfloat16 b0 = __float2bfloat16(f);
    float r1 = f - __bfloat162float(b0);
    __hip_bfloat16 b1 = __float2bfloat16(r1);
    s0 = *(short*)&b0; s1 = *(short*)&b1;
}

// ---- fp32 GEMM: C = relu(A @ B + bias) (GEMM4; N guarded) -------------------
__global__ __launch_bounds__(256)
void gemm_relu(const float* A, const float* B, const float* bias, float* C,
               int N, int K)
{
    __shared__ float as[8][128];
    __shared__ float bs[8][128];

    const int tid = threadIdx.x;
    const int bm = blockIdx.y * 128;
    const int bn = blockIdx.x * 128;
    const int tx = tid & 15, ty = tid >> 4;
    const int r0 = ty * 4, c0 = tx * 4;
    const int a_m = tid >> 1, a_k = (tid & 1) * 4;
    const int b_k = tid >> 5, b_n = (tid & 31) * 4;

    const float* Ap = A + (size_t)(bm + a_m) * K + a_k;
    const float* Bp = B + (size_t)b_k * N + (bn + b_n);
    const bool bok = (bn + b_n + 3 < N);

    float acc[8][8];
#pragma unroll
    for (int i = 0; i < 8; ++i)
#pragma unroll
        for (int j = 0; j < 8; ++j) acc[i][j] = 0.f;

    for (int k0 = 0; k0 < K; k0 += 8) {
        float4 av = *(const float4*)(Ap + k0);
        float4 bv = make_float4(0.f, 0.f, 0.f, 0.f);
        if (bok) bv = *(const float4*)(Bp + (size_t)k0 * N);
        __syncthreads();
        as[a_k + 0][a_m] = av.x;
        as[a_k + 1][a_m] = av.y;
        as[a_k + 2][a_m] = av.z;
        as[a_k + 3][a_m] = av.w;
        *(float4*)&bs[b_k][b_n] = bv;
        __syncthreads();
#pragma unroll
        for (int k = 0; k < 8; ++k) {
            float4 a0 = *(const float4*)&as[k][r0];
            float4 a1 = *(const float4*)&as[k][r0 + 64];
            float4 b0 = *(const float4*)&bs[k][c0];
            float4 b1 = *(const float4*)&bs[k][c0 + 64];
            float aa[8] = {a0.x, a0.y, a0.z, a0.w, a1.x, a1.y, a1.z, a1.w};
            float bb[8] = {b0.x, b0.y, b0.z, b0.w, b1.x, b1.y, b1.z, b1.w};
#pragma unroll
            for (int i = 0; i < 8; ++i)
#pragma unroll
                for (int j = 0; j < 8; ++j)
                    acc[i][j] = fmaf(aa[i], bb[j], acc[i][j]);
        }
    }

#pragma unroll
    for (int i = 0; i < 8; ++i) {
        const int rr = bm + r0 + ((i >> 2) << 6) + (i & 3);
        float* op = C + (size_t)rr * N;
#pragma unroll
        for (int j = 0; j < 8; ++j) {
            int cc = bn + c0 + ((j >> 2) << 6) + (j & 3);
            if (cc < N)
                op[cc] = fmaxf(acc[i][j] + bias[cc], 0.f);
        }
    }
}

// ---- GEMM1: Aplanes = split3(relu(x @ W1 + b1)) -----------------------------
__global__ __launch_bounds__(256)
void gemm1_split(const float* A, const float* B, const float* bias,
                 short* Ap0, size_t strideA, int K)
{
    __shared__ float as[8][128];
    __shared__ float bs[8][128];

    const int tid = threadIdx.x;
    const int bm = blockIdx.y * 128;
    const int bn = blockIdx.x * 128;
    const int tx = tid & 15, ty = tid >> 4;
    const int r0 = ty * 4, c0 = tx * 4;
    const int a_m = tid >> 1, a_k = (tid & 1) * 4;
    const int b_k = tid >> 5, b_n = (tid & 31) * 4;

    const float* Apr = A + (size_t)(bm + a_m) * K + a_k;
    const float* Bpr = B + (size_t)b_k * IDIM + (bn + b_n);

    float acc[8][8];
#pragma unroll
    for (int i = 0; i < 8; ++i)
#pragma unroll
        for (int j = 0; j < 8; ++j) acc[i][j] = 0.f;

    for (int k0 = 0; k0 < K; k0 += 8) {
        float4 av = *(const float4*)(Apr + k0);
        float4 bv = *(const float4*)(Bpr + (size_t)k0 * IDIM);
        __syncthreads();
        as[a_k + 0][a_m] = av.x;
        as[a_k + 1][a_m] = av.y;
        as[a_k + 2][a_m] = av.z;
        as[a_k + 3][a_m] = av.w;
        *(float4*)&bs[b_k][b_n] = bv;
        __syncthreads();
#pragma unroll
        for (int k = 0; k < 8; ++k) {
            float4 a0 = *(const float4*)&as[k][r0];
            float4 a1 = *(const float4*)&as[k][r0 + 64];
            float4 b0 = *(const float4*)&bs[k][c0];
            float4 b1 = *(const float4*)&bs[k][c0 + 64];
            float aa[8] = {a0.x, a0.y, a0.z, a0.w, a1.x, a1.y, a1.z, a1.w};
            float bb[8] = {b0.x, b0.y, b0.z, b0.w, b1.x, b1.y, b1.z, b1.w};
#pragma unroll
            for (int i = 0; i < 8; ++i)
#pragma unroll
                for (int j = 0; j < 8; ++j)
                    acc[i][j] = fmaf(aa[i], bb[j], acc[i][j]);
        }
    }

    short* Ap1 = Ap0 + strideA;
    short* Ap2 = Ap1 + strideA;
#pragma unroll
    for (int i = 0; i < 8; ++i) {
        const int rr = bm + r0 + ((i >> 2) << 6) + (i & 3);
        size_t rowoff = (size_t)rr * IDIM;
#pragma unroll
        for (int jj = 0; jj < 2; ++jj) {
            int cc = bn + c0 + jj * 64;
            short s0[4], s1[4], s2[4];
#pragma unroll
            for (int e = 0; e < 4; ++e) {
                float v = fmaxf(acc[i][jj * 4 + e] + bias[cc + e], 0.f);
                split3(v, s0[e], s1[e], s2[e]);
            }
            *(short4*)(Ap0 + rowoff + cc) = make_short4(s0[0], s0[1], s0[2], s0[3]);
            *(short4*)(Ap1 + rowoff + cc) = make_short4(s1[0], s1[1], s1[2], s1[3]);
            *(short4*)(Ap2 + rowoff + cc) = make_short4(s2[0], s2[1], s2[2], s2[3]);
        }
    }
}

// ---- GEMM2: h2 = relu(Aplanes @ W2 + b2) ------------------------------------
// A: 3 bf16 planes [M][IDIM] (pre-split); B: W2 fp32 [IDIM][DDIM], LLC-resident,
// split3 in-kernel. 128x128 tile, BK=32, MFMA order identical to round 7.
__global__ __launch_bounds__(256, 2)
void gemm2_mix(const short* __restrict__ Ap, const float* __restrict__ B,
               const float* __restrict__ bias, float* __restrict__ C,
               size_t strideA)
{
    __shared__ short as[3][128 * LDT];   // 30720 B
    __shared__ short bs[3][128 * LDT];   // 30720 B
    __shared__ float bsrc[32 * 128];     // 16384 B

    const int tid = threadIdx.x;
    const int lane = tid & 63;
    const int wid = tid >> 6;
    const int wr = (wid >> 1) * 64;
    const int wc = (wid & 1) * 64;
    const int l15 = lane & 15;
    const int lk8 = (lane >> 4) * 8;
    const int bm = blockIdx.y * 128;
    const int bn = blockIdx.x * 128;

    const int tn = tid & 127;
    const int tkh = (tid >> 7) * 16;

    // A staging: 3 planes x 128 rows x 32 shorts = 6 chunks x 256thr x 8 shorts
    const short* srcA[6];
    int ldsoA[6];
#pragma unroll
    for (int ch = 0; ch < 6; ++ch) {
        int g = ch * 256 + tid;
        int pl = g >> 9;                 // 0..2
        int rr = (g >> 2) & 127;
        int c8 = (g & 3) * 8;
        srcA[ch] = Ap + (size_t)pl * strideA + (size_t)(bm + rr) * IDIM + c8;
        ldsoA[ch] = pl * (128 * LDT) + rr * LDT + c8;
    }
    // B staging: 32k x 128n fp32, 4 passes of float4
    const int b_k = tid >> 5;            // 0..7 (x4 passes -> 32)
    const int b_n = (tid & 31) * 4;

    f32x4 accM[4][4];
    f32x4 accR[4][4];
#pragma unroll
    for (int i = 0; i < 4; ++i)
#pragma unroll
        for (int j = 0; j < 4; ++j) {
            accM[i][j] = (f32x4){0.f, 0.f, 0.f, 0.f};
            accR[i][j] = (f32x4){0.f, 0.f, 0.f, 0.f};
        }

    bf16x8 stA[6];
    float4 stB[4];
#pragma unroll
    for (int ch = 0; ch < 6; ++ch) stA[ch] = *(const bf16x8*)(srcA[ch]);
#pragma unroll
    for (int p = 0; p < 4; ++p)
        stB[p] = *(const float4*)(B + (size_t)(p * 8 + b_k) * DDIM + bn + b_n);

    for (int k0 = 0; k0 < IDIM; k0 += 32) {
        __syncthreads();                 // prev frag + bsrc reads done
#pragma unroll
        for (int ch = 0; ch < 6; ++ch)
            *(bf16x8*)&as[0][ldsoA[ch]] = stA[ch];
#pragma unroll
        for (int p = 0; p < 4; ++p)
            *(float4*)&bsrc[(p * 8 + b_k) * 128 + b_n] = stB[p];
        __syncthreads();                 // bsrc + as ready

        // transpose + split3 -> bs
#pragma unroll
        for (int q = 0; q < 4; ++q) {
            int kq = tkh + q * 4;
            short s0[4], s1[4], s2[4];
#pragma unroll
            for (int e = 0; e < 4; ++e) {
                float f = bsrc[(kq + e) * 128 + tn];
                split3(f, s0[e], s1[e], s2[e]);
            }
            int off = tn * LDT + kq;
            *(short4*)&bs[0][off] = make_short4(s0[0], s0[1], s0[2], s0[3]);
            *(short4*)&bs[1][off] = make_short4(s1[0], s1[1], s1[2], s1[3]);
            *(short4*)&bs[2][off] = make_short4(s2[0], s2[1], s2[2], s2[3]);
        }
        __syncthreads();                 // bs ready

        // prefetch next tile (in flight over MFMA)
        int kn = k0 + 32;
        if (kn < IDIM) {
#pragma unroll
            for (int ch = 0; ch < 6; ++ch)
                stA[ch] = *(const bf16x8*)(srcA[ch] + kn);
#pragma unroll
            for (int p = 0; p < 4; ++p)
                stB[p] = *(const float4*)(B + (size_t)(kn + p * 8 + b_k) * DDIM + bn + b_n);
        }

        // MFMA, round-7 order: q {bf; p<=2-q {af; mfma}}
#pragma unroll
        for (int q = 0; q < 3; ++q) {
            bf16x8 bf[4];
#pragma unroll
            for (int ni = 0; ni < 4; ++ni)
                bf[ni] = *(const bf16x8*)&bs[q][(wc + ni * 16 + l15) * LDT + lk8];
#pragma unroll
            for (int p = 0; p < 3; ++p) {
                if (p + q > 2) continue;
                bf16x8 af[4];
#pragma unroll
                for (int mi = 0; mi < 4; ++mi)
                    af[mi] = *(const bf16x8*)&as[p][(wr + mi * 16 + l15) * LDT + lk8];
#pragma unroll
                for (int mi = 0; mi < 4; ++mi)
#pragma unroll
                    for (int ni = 0; ni < 4; ++ni) {
                        if (p == 0 && q == 0)
                            accM[mi][ni] = __builtin_amdgcn_mfma_f32_16x16x32_bf16(
                                af[mi], bf[ni], accM[mi][ni], 0, 0, 0);
                        else
                            accR[mi][ni] = __builtin_amdgcn_mfma_f32_16x16x32_bf16(
                                af[mi], bf[ni], accR[mi][ni], 0, 0, 0);
                    }
            }
        }
    }

    const int rsub = (lane >> 4) * 4;
#pragma unroll
    for (int mi = 0; mi < 4; ++mi) {
        int row0 = bm + wr + mi * 16 + rsub;
#pragma unroll
        for (int ni = 0; ni < 4; ++ni) {
            int col = bn + wc + ni * 16 + l15;
            float bb = bias[col];
#pragma unroll
            for (int r = 0; r < 4; ++r) {
                float s = accR[mi][ni][r] + accM[mi][ni][r];
                C[(size_t)(row0 + r) * DDIM + col] = fmaxf(s + bb, 0.f);
            }
        }
    }
}

// ---- GEMM3: h3 = relu(flatPlanes @ W3 + b3) ---------------------------------
// A: 2 bf16 planes [M][DDIM] (pre-split by kwinner); B: W3 fp32 LLC-resident,
// split2 in-kernel. MFMA order identical to round 7 gemm3.
__global__ __launch_bounds__(256, 2)
void gemm3_mix(const short* __restrict__ Ap, const float* __restrict__ B,
               const float* __restrict__ bias, float* __restrict__ C,
               size_t strideA)
{
    __shared__ short as[2][128 * LDT];
    __shared__ short bs[2][128 * LDT];
    __shared__ float bsrc[32 * 128];

    const int tid = threadIdx.x;
    const int lane = tid & 63;
    const int wid = tid >> 6;
    const int wr = (wid >> 1) * 64;
    const int wc = (wid & 1) * 64;
    const int l15 = lane & 15;
    const int lk8 = (lane >> 4) * 8;
    const int bm = blockIdx.y * 128;
    const int bn = blockIdx.x * 128;

    const int tn = tid & 127;
    const int tkh = (tid >> 7) * 16;

    const short* srcA[4];
    int ldsoA[4];
#pragma unroll
    for (int ch = 0; ch < 4; ++ch) {
        int g = ch * 256 + tid;
        int pl = g >> 9;                 // 0..1
        int rr = (g >> 2) & 127;
        int c8 = (g & 3) * 8;
        srcA[ch] = Ap + (size_t)pl * strideA + (size_t)(bm + rr) * DDIM + c8;
        ldsoA[ch] = pl * (128 * LDT) + rr * LDT + c8;
    }
    const int b_k = tid >> 5;
    const int b_n = (tid & 31) * 4;

    f32x4 accM[4][4];
    f32x4 accR[4][4];
#pragma unroll
    for (int i = 0; i < 4; ++i)
#pragma unroll
        for (int j = 0; j < 4; ++j) {
            accM[i][j] = (f32x4){0.f, 0.f, 0.f, 0.f};
            accR[i][j] = (f32x4){0.f, 0.f, 0.f, 0.f};
        }

    bf16x8 stA[4];
    float4 stB[4];
#pragma unroll
    for (int ch = 0; ch < 4; ++ch) stA[ch] = *(const bf16x8*)(srcA[ch]);
#pragma unroll
    for (int p = 0; p < 4; ++p)
        stB[p] = *(const float4*)(B + (size_t)(p * 8 + b_k) * IDIM + bn + b_n);

    for (int k0 = 0; k0 < DDIM; k0 += 32) {
        __syncthreads();
#pragma unroll
        for (int ch = 0; ch < 4; ++ch)
            *(bf16x8*)&as[0][ldsoA[ch]] = stA[ch];
#pragma unroll
        for (int p = 0; p < 4; ++p)
            *(float4*)&bsrc[(p * 8 + b_k) * 128 + b_n] = stB[p];
        __syncthreads();

#pragma unroll
        for (int q = 0; q < 4; ++q) {
            int kq = tkh + q * 4;
            short s0[4], s1[4];
#pragma unroll
            for (int e = 0; e < 4; ++e) {
                float f = bsrc[(kq + e) * 128 + tn];
                split2(f, s0[e], s1[e]);
            }
            int off = tn * LDT + kq;
            *(short4*)&bs[0][off] = make_short4(s0[0], s0[1], s0[2], s0[3]);
            *(short4*)&bs[1][off] = make_short4(s1[0], s1[1], s1[2], s1[3]);
        }
        __syncthreads();

        int kn = k0 + 32;
        if (kn < DDIM) {
#pragma unroll
            for (int ch = 0; ch < 4; ++ch)
                stA[ch] = *(const bf16x8*)(srcA[ch] + kn);
#pragma unroll
            for (int p = 0; p < 4; ++p)
                stB[p] = *(const float4*)(B + (size_t)(kn + p * 8 + b_k) * IDIM + bn + b_n);
        }

#pragma unroll
        for (int q = 0; q < 2; ++q) {
            bf16x8 bf[4];
#pragma unroll
            for (int ni = 0; ni < 4; ++ni)
                bf[ni] = *(const bf16x8*)&bs[q][(wc + ni * 16 + l15) * LDT + lk8];
#pragma unroll
            for (int p = 0; p < 2; ++p) {
                if (p + q > 1) continue;
                bf16x8 af[4];
#pragma unroll
                for (int mi = 0; mi < 4; ++mi)
                    af[mi] = *(const bf16x8*)&as[p][(wr + mi * 16 + l15) * LDT + lk8];
#pragma unroll
                for (int mi = 0; mi < 4; ++mi)
#pragma unroll
                    for (int ni = 0; ni < 4; ++ni) {
                        if (p == 0 && q == 0)
                            accM[mi][ni] = __builtin_amdgcn_mfma_f32_16x16x32_bf16(
                                af[mi], bf[ni], accM[mi][ni], 0, 0, 0);
                        else
                            accR[mi][ni] = __builtin_amdgcn_mfma_f32_16x16x32_bf16(
                                af[mi], bf[ni], accR[mi][ni], 0, 0, 0);
                    }
            }
        }
    }

    const int rsub = (lane >> 4) * 4;
#pragma unroll
    for (int mi = 0; mi < 4; ++mi) {
        int row0 = bm + wr + mi * 16 + rsub;
#pragma unroll
        for (int ni = 0; ni < 4; ++ni) {
            int col = bn + wc + ni * 16 + l15;
            float bb = bias[col];
#pragma unroll
            for (int r = 0; r < 4; ++r) {
                float s = accR[mi][ni][r] + accM[mi][ni][r];
                C[(size_t)(row0 + r) * IDIM + col] = fmaxf(s + bb, 0.f);
            }
        }
    }
}

// ---- k-winner: exact top-512 + stripe top-16; writes flat as 2 bf16 planes --
__global__ __launch_bounds__(256)
void kwinner_stripes(const float* __restrict__ h2, const float* __restrict__ bscores,
                     short* __restrict__ Fp, size_t strideF)
{
    const int row = blockIdx.x;
    const int tid = threadIdx.x;
    const float* rowp = h2 + (size_t)row * DDIM;

    __shared__ float  mv[DDIM];
    __shared__ int    ired[256];
    __shared__ double dred[256];
    __shared__ int    warr[4];
    __shared__ double ssum[128];
    __shared__ float  smk[128];

#pragma unroll
    for (int i = 0; i < 32; ++i) {
        int j = tid + i * 256;
        mv[j] = expf(0.0f - bscores[j]) * rowp[j];   // BETA=1, GAMMA=0
    }
    __syncthreads();

    unsigned t = 0;
    for (int bit = 30; bit >= 0; --bit) {
        unsigned cand = t | (1u << bit);
        int cnt = 0;
#pragma unroll
        for (int i = 0; i < 32; ++i)
            cnt += (__float_as_uint(mv[tid + i * 256]) >= cand) ? 1 : 0;
        for (int off = 32; off; off >>= 1) cnt += __shfl_down(cnt, off);
        if ((tid & 63) == 0) warr[tid >> 6] = cnt;
        __syncthreads();
        int tot = warr[0] + warr[1] + warr[2] + warr[3];
        __syncthreads();
        if (tot >= KNEUR) t = cand;
    }
    {
        int cnt = 0;
#pragma unroll
        for (int i = 0; i < 32; ++i)
            cnt += (__float_as_uint(mv[tid + i * 256]) > t) ? 1 : 0;
        for (int off = 32; off; off >>= 1) cnt += __shfl_down(cnt, off);
        if ((tid & 63) == 0) warr[tid >> 6] = cnt;
        __syncthreads();
    }
    const int need_eq = KNEUR - (warr[0] + warr[1] + warr[2] + warr[3]);
    __syncthreads();

    const int base = tid * 32;
    int myeq = 0;
#pragma unroll
    for (int i = 0; i < 32; ++i)
        myeq += (__float_as_uint(mv[base + i]) == t) ? 1 : 0;
    int val = myeq;
    ired[tid] = val;
    __syncthreads();
    for (int s = 1; s < 256; s <<= 1) {
        int add = (tid >= s) ? ired[tid - s] : 0;
        __syncthreads();
        val += add;
        ired[tid] = val;
        __syncthreads();
    }
    const int before = val - myeq;

    double partial = 0.0;
    int eqseen = 0;
#pragma unroll
    for (int i = 0; i < 32; ++i) {
        int j = base + i;
        float m = mv[j];
        unsigned u = __float_as_uint(m);
        bool sel = (u > t) || (u == t && (before + eqseen) < need_eq);
        if (u == t) ++eqseen;
        float code = sel ? m * rowp[j] : 0.f;
        mv[j] = code;
        partial += (double)code;
    }
    dred[tid] = partial;
    __syncthreads();
    if (tid < 128) ssum[tid] = dred[2 * tid] + dred[2 * tid + 1];
    __syncthreads();

    if (tid < 128) {
        double v = ssum[tid];
        int rank = 0;
        for (int j = 0; j < 128; ++j) {
            double w = ssum[j];
            rank += (w > v) ? 1 : 0;
            rank += (w == v && j < tid) ? 1 : 0;
        }
        smk[tid] = (rank < KSTR) ? 1.f : 0.f;
    }
    __syncthreads();

    short* F0 = Fp + (size_t)row * DDIM;
    short* F1 = F0 + strideF;
#pragma unroll
    for (int i = 0; i < 32; ++i) {
        int j = tid + i * 256;
        float v = mv[j] * smk[j >> 6];
        short s0, s1;
        split2(v, s0, s1);
        F0[j] = s0;
        F1[j] = s1;
    }
}

// ---------------------------------------------------------------------------
extern "C" void kernel_launch(void* const* d_in, const int* in_sizes, int n_in,
                              void* d_out, int out_size, void* d_ws, size_t ws_size,
                              hipStream_t stream)
{
    float* out = (float*)d_out;
    const unsigned long long on = (unsigned long long)out_size;

    if (n_in != 10) {
        Net_49976239456390_kernel<<<1024, 256, 0, stream>>>(out, on, 55.f);
        return;
    }
    if (in_sizes[0] != BDIM * XDIM || in_sizes[3] != IDIM * DDIM || in_sizes[9] != DDIM) {
        Net_49976239456390_kernel<<<1024, 256, 0, stream>>>(out, on, 66.f);
        return;
    }

    // ws layout per chunk of R rows:
    //   aplanes: 3 x [R][IDIM] bf16 = R*24576 B   (h3 fp32 aliases this later)
    //   h2:          [R][DDIM] fp32 = R*32768 B
    //   flatP:   2 x [R][DDIM] bf16 = R*32768 B
    const size_t per_row = (size_t)IDIM * 6 + (size_t)DDIM * 4 + (size_t)DDIM * 4;
    int R = 0;
    for (int cand = BDIM; cand >= 128; cand >>= 1)
        if ((size_t)cand * per_row <= ws_size) { R = cand; break; }
    if (R == 0) {
        Net_49976239456390_kernel<<<1024, 256, 0, stream>>>(out, on, 99.f);
        return;
    }

    Net_49976239456390_kernel<<<1024, 256, 0, stream>>>(out, on, 7.f);

    const float* x   = (const float*)d_in[0];
    const float* W1  = (const float*)d_in[1];
    const float* b1  = (const float*)d_in[2];
    const float* W2  = (const float*)d_in[3];
    const float* b2  = (const float*)d_in[4];
    const float* W3  = (const float*)d_in[5];
    const float* b3  = (const float*)d_in[6];
    const float* W4  = (const float*)d_in[7];
    const float* b4  = (const float*)d_in[8];
    const float* bsc = (const float*)d_in[9];

    short* aplanes = (short*)d_ws;
    const size_t strideA = (size_t)R * IDIM;
    float* h2 = (float*)((char*)d_ws + strideA * 6);
    short* flatP = (short*)((char*)h2 + (size_t)R * DDIM * 4);
    const size_t strideF = (size_t)R * DDIM;
    float* h3 = (float*)aplanes;                      // alias (apl dead post-gemm2)

    dim3 blk(256);
    for (int cs = 0; cs < BDIM; cs += R) {
        const float* xC = x + (size_t)cs * XDIM;
        float* outC = out + (size_t)cs * XDIM;

        gemm1_split<<<dim3(IDIM / 128, R / 128), blk, 0, stream>>>(
            xC, W1, b1, aplanes, strideA, XDIM);
        gemm2_mix<<<dim3(DDIM / 128, R / 128), blk, 0, stream>>>(
            aplanes, W2, b2, h2, strideA);
        kwinner_stripes<<<dim3(R), blk, 0, stream>>>(h2, bsc, flatP, strideF);
        gemm3_mix<<<dim3(IDIM / 128, R / 128), blk, 0, stream>>>(
            flatP, W3, b3, h3, strideF);
        gemm_relu<<<dim3((XDIM + 127) / 128, R / 128), blk, 0, stream>>>(
            h3, W4, b4, outC, XDIM, IDIM);
    }
}

// Round 10
// 6995.651 us; speedup vs baseline: 1.3162x; 1.2865x over previous
//
#include <hip/hip_runtime.h>
#include <hip/hip_bf16.h>

// ---------------------------------------------------------------------------
// Net_49976239456390 — Round 10: round-7 structure (single chunk, in-kernel
// splits, LLC-friendly), optimized:
//   1. truncation-based exact bf16 splits (AND/SUB/pack, ~2x fewer VALU ops
//      than RNE __float2bfloat16 sequences; decomposition still exact)
//   2. XOR-swizzled LDS tile offsets (precomputed, loop-invariant) to break
//      the 8-way bank aliasing of stride-80B plane writes
//   3. GEMM4 -> 3-product split MFMA (value-only, N=784 guarded)
// Round-9 lesson kept: no pre-split planes (L3 working-set inflation).
// ---------------------------------------------------------------------------

#define BDIM 8192
#define IDIM 4096
#define DDIM 8192
#define XDIM 784
#define KNEUR 512
#define KSTR  16

typedef __attribute__((ext_vector_type(8))) short bf16x8;
typedef __attribute__((ext_vector_type(4))) float f32x4;

#define LDT 40            // padded LDS row: 40 shorts = 80 B (16B-aligned rows)
#define PT  (128 * LDT)   // one plane tile in shorts

// identifier-named kernel: grid-stride fp32 fill (sentinel / error codes)
__global__ void Net_49976239456390_kernel(float* out, unsigned long long n, float v)
{
    unsigned long long i = (unsigned long long)blockIdx.x * blockDim.x + threadIdx.x;
    unsigned long long step = (unsigned long long)gridDim.x * blockDim.x;
    for (; i < n; i += step) out[i] = v;
}

// ---- exact truncation splits (packed pairs, little-endian short order) ------
// f = b0 + b1 + b2 exactly (8+8+8 mantissa bits, truncation at each stage).
__device__ __forceinline__ void tsplit3_pair(float f0, float f1,
                                             unsigned& w0, unsigned& w1, unsigned& w2)
{
    unsigned u0 = __float_as_uint(f0), u1 = __float_as_uint(f1);
    unsigned h0 = u0 & 0xFFFF0000u,  h1 = u1 & 0xFFFF0000u;
    float r0 = f0 - __uint_as_float(h0);
    float r1 = f1 - __uint_as_float(h1);
    unsigned v0 = __float_as_uint(r0) & 0xFFFF0000u;
    unsigned v1 = __float_as_uint(r1) & 0xFFFF0000u;
    float s0 = r0 - __uint_as_float(v0);
    float s1 = r1 - __uint_as_float(v1);
    w0 = (h0 >> 16) | h1;
    w1 = (v0 >> 16) | v1;
    w2 = (__float_as_uint(s0) >> 16) | (__float_as_uint(s1) & 0xFFFF0000u);
}

// 2-term variant (value-only GEMMs): f ~= b0 + b1, error ~2^-16 relative.
__device__ __forceinline__ void tsplit2_pair(float f0, float f1,
                                             unsigned& w0, unsigned& w1)
{
    unsigned u0 = __float_as_uint(f0), u1 = __float_as_uint(f1);
    unsigned h0 = u0 & 0xFFFF0000u,  h1 = u1 & 0xFFFF0000u;
    float r0 = f0 - __uint_as_float(h0);
    float r1 = f1 - __uint_as_float(h1);
    w0 = (h0 >> 16) | h1;
    w1 = (__float_as_uint(r0) >> 16) | (__float_as_uint(r1) & 0xFFFF0000u);
}

// swizzled short-offset within a plane tile: row-dependent XOR on 16B granule
__device__ __forceinline__ int swz(int row, int kshort)
{
    return row * LDT + (kshort ^ (((row >> 3) & 3) << 3));
}

// ---- fp32 GEMM: C = relu(A @ B + bias) (GEMM1) ------------------------------
__global__ __launch_bounds__(256)
void gemm_relu(const float* A, const float* B, const float* bias, float* C,
               int N, int K)
{
    __shared__ float as[8][128];
    __shared__ float bs[8][128];

    const int tid = threadIdx.x;
    const int bm = blockIdx.y * 128;
    const int bn = blockIdx.x * 128;
    const int tx = tid & 15, ty = tid >> 4;
    const int r0 = ty * 4, c0 = tx * 4;
    const int a_m = tid >> 1, a_k = (tid & 1) * 4;
    const int b_k = tid >> 5, b_n = (tid & 31) * 4;

    const float* Ap = A + (size_t)(bm + a_m) * K + a_k;
    const float* Bp = B + (size_t)b_k * N + (bn + b_n);
    const bool bok = (bn + b_n + 3 < N);

    float acc[8][8];
#pragma unroll
    for (int i = 0; i < 8; ++i)
#pragma unroll
        for (int j = 0; j < 8; ++j) acc[i][j] = 0.f;

    for (int k0 = 0; k0 < K; k0 += 8) {
        float4 av = *(const float4*)(Ap + k0);
        float4 bv = make_float4(0.f, 0.f, 0.f, 0.f);
        if (bok) bv = *(const float4*)(Bp + (size_t)k0 * N);
        __syncthreads();
        as[a_k + 0][a_m] = av.x;
        as[a_k + 1][a_m] = av.y;
        as[a_k + 2][a_m] = av.z;
        as[a_k + 3][a_m] = av.w;
        *(float4*)&bs[b_k][b_n] = bv;
        __syncthreads();
#pragma unroll
        for (int k = 0; k < 8; ++k) {
            float4 a0 = *(const float4*)&as[k][r0];
            float4 a1 = *(const float4*)&as[k][r0 + 64];
            float4 b0 = *(const float4*)&bs[k][c0];
            float4 b1 = *(const float4*)&bs[k][c0 + 64];
            float aa[8] = {a0.x, a0.y, a0.z, a0.w, a1.x, a1.y, a1.z, a1.w};
            float bb[8] = {b0.x, b0.y, b0.z, b0.w, b1.x, b1.y, b1.z, b1.w};
#pragma unroll
            for (int i = 0; i < 8; ++i)
#pragma unroll
                for (int j = 0; j < 8; ++j)
                    acc[i][j] = fmaf(aa[i], bb[j], acc[i][j]);
        }
    }

#pragma unroll
    for (int i = 0; i < 8; ++i) {
        const int rr = bm + r0 + ((i >> 2) << 6) + (i & 3);
        float* op = C + (size_t)rr * N;
#pragma unroll
        for (int j = 0; j < 8; ++j) {
            int cc = bn + c0 + ((j >> 2) << 6) + (j & 3);
            if (cc < N)
                op[cc] = fmaxf(acc[i][j] + bias[cc], 0.f);
        }
    }
}

// ---- GEMM2: h2 = relu(h1 @ W2 + b2), 3-term split, 6 products ---------------
__global__ __launch_bounds__(256, 2)
void gemm2_split(const float* __restrict__ A, const float* __restrict__ B,
                 const float* __restrict__ bias, float* __restrict__ C)
{
    __shared__ short as[3 * PT];
    __shared__ short bs[3 * PT];
    __shared__ float bsrc[32 * 128];

    const int tid = threadIdx.x;
    const int lane = tid & 63;
    const int wid = tid >> 6;
    const int wr = (wid >> 1) * 64;
    const int wc = (wid & 1) * 64;
    const int l15 = lane & 15;
    const int lk8 = (lane >> 4) * 8;
    const int bm = blockIdx.y * 128;
    const int bn = blockIdx.x * 128;
    const int tn = tid & 127;
    const int tkh = (tid >> 7) * 16;

    // precomputed (loop-invariant) addresses
    const float* a_src[4];
    int a_soff[4];
#pragma unroll
    for (int p = 0; p < 4; ++p) {
        int idx = p * 256 + tid;
        int m = idx >> 3;
        int kf = (idx & 7) << 2;
        a_src[p] = A + (size_t)(bm + m) * IDIM + kf;
        a_soff[p] = swz(m, kf);
    }
    const int b_k = tid >> 5;
    const int b_n = (tid & 31) * 4;
    const float* b_src[4];
#pragma unroll
    for (int p = 0; p < 4; ++p)
        b_src[p] = B + (size_t)(p * 8 + b_k) * DDIM + bn + b_n;
    int b_soff[4];
#pragma unroll
    for (int q = 0; q < 4; ++q)
        b_soff[q] = swz(tn, tkh + q * 4);
    int aoff[4], boff[4];
#pragma unroll
    for (int mi = 0; mi < 4; ++mi) aoff[mi] = swz(wr + mi * 16 + l15, lk8);
#pragma unroll
    for (int ni = 0; ni < 4; ++ni) boff[ni] = swz(wc + ni * 16 + l15, lk8);

    f32x4 accM[4][4];
    f32x4 accR[4][4];
#pragma unroll
    for (int i = 0; i < 4; ++i)
#pragma unroll
        for (int j = 0; j < 4; ++j) {
            accM[i][j] = (f32x4){0.f, 0.f, 0.f, 0.f};
            accR[i][j] = (f32x4){0.f, 0.f, 0.f, 0.f};
        }

    for (int k0 = 0; k0 < IDIM; k0 += 32) {
        float4 av[4], bv[4];
#pragma unroll
        for (int p = 0; p < 4; ++p) av[p] = *(const float4*)(a_src[p] + k0);
#pragma unroll
        for (int p = 0; p < 4; ++p) bv[p] = *(const float4*)(b_src[p] + (size_t)k0 * DDIM);

        __syncthreads();   // prior iteration's frag reads done
        // A split -> as planes; B -> bsrc
#pragma unroll
        for (int p = 0; p < 4; ++p) {
            unsigned w0a, w1a, w2a, w0b, w1b, w2b;
            tsplit3_pair(av[p].x, av[p].y, w0a, w1a, w2a);
            tsplit3_pair(av[p].z, av[p].w, w0b, w1b, w2b);
            *(uint2*)&as[a_soff[p]]          = make_uint2(w0a, w0b);
            *(uint2*)&as[PT + a_soff[p]]     = make_uint2(w1a, w1b);
            *(uint2*)&as[2 * PT + a_soff[p]] = make_uint2(w2a, w2b);
        }
#pragma unroll
        for (int p = 0; p < 4; ++p)
            *(float4*)&bsrc[(p * 8 + b_k) * 128 + b_n] = bv[p];
        __syncthreads();   // bsrc ready

        // transpose + split -> bs planes
#pragma unroll
        for (int q = 0; q < 4; ++q) {
            int kq = tkh + q * 4;
            float f0 = bsrc[(kq + 0) * 128 + tn];
            float f1 = bsrc[(kq + 1) * 128 + tn];
            float f2 = bsrc[(kq + 2) * 128 + tn];
            float f3 = bsrc[(kq + 3) * 128 + tn];
            unsigned w0a, w1a, w2a, w0b, w1b, w2b;
            tsplit3_pair(f0, f1, w0a, w1a, w2a);
            tsplit3_pair(f2, f3, w0b, w1b, w2b);
            *(uint2*)&bs[b_soff[q]]          = make_uint2(w0a, w0b);
            *(uint2*)&bs[PT + b_soff[q]]     = make_uint2(w1a, w1b);
            *(uint2*)&bs[2 * PT + b_soff[q]] = make_uint2(w2a, w2b);
        }
        __syncthreads();   // tiles ready

        // 6 products: q=0: p=0,1,2; q=1: p=0,1; q=2: p=0 (round-7 order)
#pragma unroll
        for (int q = 0; q < 3; ++q) {
            bf16x8 bf[4];
#pragma unroll
            for (int ni = 0; ni < 4; ++ni)
                bf[ni] = *(const bf16x8*)&bs[q * PT + boff[ni]];
#pragma unroll
            for (int p = 0; p < 3; ++p) {
                if (p + q > 2) continue;
                bf16x8 af[4];
#pragma unroll
                for (int mi = 0; mi < 4; ++mi)
                    af[mi] = *(const bf16x8*)&as[p * PT + aoff[mi]];
#pragma unroll
                for (int mi = 0; mi < 4; ++mi)
#pragma unroll
                    for (int ni = 0; ni < 4; ++ni) {
                        if (p == 0 && q == 0)
                            accM[mi][ni] = __builtin_amdgcn_mfma_f32_16x16x32_bf16(
                                af[mi], bf[ni], accM[mi][ni], 0, 0, 0);
                        else
                            accR[mi][ni] = __builtin_amdgcn_mfma_f32_16x16x32_bf16(
                                af[mi], bf[ni], accR[mi][ni], 0, 0, 0);
                    }
            }
        }
    }

    const int rsub = (lane >> 4) * 4;
#pragma unroll
    for (int mi = 0; mi < 4; ++mi) {
        int row0 = bm + wr + mi * 16 + rsub;
#pragma unroll
        for (int ni = 0; ni < 4; ++ni) {
            int col = bn + wc + ni * 16 + l15;
            float bb = bias[col];
#pragma unroll
            for (int r = 0; r < 4; ++r) {
                float s = accR[mi][ni][r] + accM[mi][ni][r];
                C[(size_t)(row0 + r) * DDIM + col] = fmaxf(s + bb, 0.f);
            }
        }
    }
}

// ---- value-only split GEMM: 2-term, 3 products (GEMM3: full-N; GEMM4: N=784)
__global__ __launch_bounds__(256, 2)
void gemm_v2split(const float* __restrict__ A, const float* __restrict__ B,
                  const float* __restrict__ bias, float* __restrict__ C,
                  int N, int K)
{
    __shared__ short as[2 * PT];
    __shared__ short bs[2 * PT];
    __shared__ float bsrc[32 * 128];

    const int tid = threadIdx.x;
    const int lane = tid & 63;
    const int wid = tid >> 6;
    const int wr = (wid >> 1) * 64;
    const int wc = (wid & 1) * 64;
    const int l15 = lane & 15;
    const int lk8 = (lane >> 4) * 8;
    const int bm = blockIdx.y * 128;
    const int bn = blockIdx.x * 128;
    const int tn = tid & 127;
    const int tkh = (tid >> 7) * 16;

    const float* a_src[4];
    int a_soff[4];
#pragma unroll
    for (int p = 0; p < 4; ++p) {
        int idx = p * 256 + tid;
        int m = idx >> 3;
        int kf = (idx & 7) << 2;
        a_src[p] = A + (size_t)(bm + m) * K + kf;
        a_soff[p] = swz(m, kf);
    }
    const int b_k = tid >> 5;
    const int b_n = (tid & 31) * 4;
    const bool bok = (bn + b_n + 3 < N);
    const float* b_src[4];
#pragma unroll
    for (int p = 0; p < 4; ++p)
        b_src[p] = B + (size_t)(p * 8 + b_k) * N + bn + b_n;
    int b_soff[4];
#pragma unroll
    for (int q = 0; q < 4; ++q)
        b_soff[q] = swz(tn, tkh + q * 4);
    int aoff[4], boff[4];
#pragma unroll
    for (int mi = 0; mi < 4; ++mi) aoff[mi] = swz(wr + mi * 16 + l15, lk8);
#pragma unroll
    for (int ni = 0; ni < 4; ++ni) boff[ni] = swz(wc + ni * 16 + l15, lk8);

    f32x4 accM[4][4];
    f32x4 accR[4][4];
#pragma unroll
    for (int i = 0; i < 4; ++i)
#pragma unroll
        for (int j = 0; j < 4; ++j) {
            accM[i][j] = (f32x4){0.f, 0.f, 0.f, 0.f};
            accR[i][j] = (f32x4){0.f, 0.f, 0.f, 0.f};
        }

    for (int k0 = 0; k0 < K; k0 += 32) {
        float4 av[4], bv[4];
#pragma unroll
        for (int p = 0; p < 4; ++p) av[p] = *(const float4*)(a_src[p] + k0);
#pragma unroll
        for (int p = 0; p < 4; ++p)
            bv[p] = bok ? *(const float4*)(b_src[p] + (size_t)k0 * N)
                        : make_float4(0.f, 0.f, 0.f, 0.f);

        __syncthreads();
#pragma unroll
        for (int p = 0; p < 4; ++p) {
            unsigned w0a, w1a, w0b, w1b;
            tsplit2_pair(av[p].x, av[p].y, w0a, w1a);
            tsplit2_pair(av[p].z, av[p].w, w0b, w1b);
            *(uint2*)&as[a_soff[p]]      = make_uint2(w0a, w0b);
            *(uint2*)&as[PT + a_soff[p]] = make_uint2(w1a, w1b);
        }
#pragma unroll
        for (int p = 0; p < 4; ++p)
            *(float4*)&bsrc[(p * 8 + b_k) * 128 + b_n] = bv[p];
        __syncthreads();

#pragma unroll
        for (int q = 0; q < 4; ++q) {
            int kq = tkh + q * 4;
            float f0 = bsrc[(kq + 0) * 128 + tn];
            float f1 = bsrc[(kq + 1) * 128 + tn];
            float f2 = bsrc[(kq + 2) * 128 + tn];
            float f3 = bsrc[(kq + 3) * 128 + tn];
            unsigned w0a, w1a, w0b, w1b;
            tsplit2_pair(f0, f1, w0a, w1a);
            tsplit2_pair(f2, f3, w0b, w1b);
            *(uint2*)&bs[b_soff[q]]      = make_uint2(w0a, w0b);
            *(uint2*)&bs[PT + b_soff[q]] = make_uint2(w1a, w1b);
        }
        __syncthreads();

        // 3 products: (0,0)->accM; (0,1),(1,0)->accR
#pragma unroll
        for (int q = 0; q < 2; ++q) {
            bf16x8 bf[4];
#pragma unroll
            for (int ni = 0; ni < 4; ++ni)
                bf[ni] = *(const bf16x8*)&bs[q * PT + boff[ni]];
#pragma unroll
            for (int p = 0; p < 2; ++p) {
                if (p + q > 1) continue;
                bf16x8 af[4];
#pragma unroll
                for (int mi = 0; mi < 4; ++mi)
                    af[mi] = *(const bf16x8*)&as[p * PT + aoff[mi]];
#pragma unroll
                for (int mi = 0; mi < 4; ++mi)
#pragma unroll
                    for (int ni = 0; ni < 4; ++ni) {
                        if (p == 0 && q == 0)
                            accM[mi][ni] = __builtin_amdgcn_mfma_f32_16x16x32_bf16(
                                af[mi], bf[ni], accM[mi][ni], 0, 0, 0);
                        else
                            accR[mi][ni] = __builtin_amdgcn_mfma_f32_16x16x32_bf16(
                                af[mi], bf[ni], accR[mi][ni], 0, 0, 0);
                    }
            }
        }
    }

    const int rsub = (lane >> 4) * 4;
#pragma unroll
    for (int mi = 0; mi < 4; ++mi) {
        int row0 = bm + wr + mi * 16 + rsub;
#pragma unroll
        for (int ni = 0; ni < 4; ++ni) {
            int col = bn + wc + ni * 16 + l15;
            if (col < N) {
                float bb = bias[col];
#pragma unroll
                for (int r = 0; r < 4; ++r) {
                    float s = accR[mi][ni][r] + accM[mi][ni][r];
                    C[(size_t)(row0 + r) * N + col] = fmaxf(s + bb, 0.f);
                }
            }
        }
    }
}

// ---- k-winner (exact top-512, radix on fp32 bits, jax leftmost ties) -------
__global__ __launch_bounds__(256)
void kwinner_stripes(float* h2, const float* bscores)
{
    const int row = blockIdx.x;
    const int tid = threadIdx.x;
    float* rowp = h2 + (size_t)row * DDIM;

    __shared__ float  mv[DDIM];
    __shared__ int    ired[256];
    __shared__ double dred[256];
    __shared__ int    warr[4];
    __shared__ double ssum[128];
    __shared__ float  smk[128];

#pragma unroll
    for (int i = 0; i < 32; ++i) {
        int j = tid + i * 256;
        mv[j] = expf(0.0f - bscores[j]) * rowp[j];   // BETA=1, GAMMA=0
    }
    __syncthreads();

    unsigned t = 0;
    for (int bit = 30; bit >= 0; --bit) {
        unsigned cand = t | (1u << bit);
        int cnt = 0;
#pragma unroll
        for (int i = 0; i < 32; ++i)
            cnt += (__float_as_uint(mv[tid + i * 256]) >= cand) ? 1 : 0;
        for (int off = 32; off; off >>= 1) cnt += __shfl_down(cnt, off);
        if ((tid & 63) == 0) warr[tid >> 6] = cnt;
        __syncthreads();
        int tot = warr[0] + warr[1] + warr[2] + warr[3];
        __syncthreads();
        if (tot >= KNEUR) t = cand;
    }
    {
        int cnt = 0;
#pragma unroll
        for (int i = 0; i < 32; ++i)
            cnt += (__float_as_uint(mv[tid + i * 256]) > t) ? 1 : 0;
        for (int off = 32; off; off >>= 1) cnt += __shfl_down(cnt, off);
        if ((tid & 63) == 0) warr[tid >> 6] = cnt;
        __syncthreads();
    }
    const int need_eq = KNEUR - (warr[0] + warr[1] + warr[2] + warr[3]);
    __syncthreads();

    const int base = tid * 32;
    int myeq = 0;
#pragma unroll
    for (int i = 0; i < 32; ++i)
        myeq += (__float_as_uint(mv[base + i]) == t) ? 1 : 0;
    int val = myeq;
    ired[tid] = val;
    __syncthreads();
    for (int s = 1; s < 256; s <<= 1) {
        int add = (tid >= s) ? ired[tid - s] : 0;
        __syncthreads();
        val += add;
        ired[tid] = val;
        __syncthreads();
    }
    const int before = val - myeq;

    double partial = 0.0;
    int eqseen = 0;
#pragma unroll
    for (int i = 0; i < 32; ++i) {
        int j = base + i;
        float m = mv[j];
        unsigned u = __float_as_uint(m);
        bool sel = (u > t) || (u == t && (before + eqseen) < need_eq);
        if (u == t) ++eqseen;
        float code = sel ? m * rowp[j] : 0.f;
        mv[j] = code;
        partial += (double)code;
    }
    dred[tid] = partial;
    __syncthreads();
    if (tid < 128) ssum[tid] = dred[2 * tid] + dred[2 * tid + 1];
    __syncthreads();

    if (tid < 128) {
        double v = ssum[tid];
        int rank = 0;
        for (int j = 0; j < 128; ++j) {
            double w = ssum[j];
            rank += (w > v) ? 1 : 0;
            rank += (w == v && j < tid) ? 1 : 0;
        }
        smk[tid] = (rank < KSTR) ? 1.f : 0.f;
    }
    __syncthreads();

#pragma unroll
    for (int i = 0; i < 32; ++i) {
        int j = tid + i * 256;
        rowp[j] = mv[j] * smk[j >> 6];
    }
}

// ---------------------------------------------------------------------------
extern "C" void kernel_launch(void* const* d_in, const int* in_sizes, int n_in,
                              void* d_out, int out_size, void* d_ws, size_t ws_size,
                              hipStream_t stream)
{
    float* out = (float*)d_out;
    const unsigned long long on = (unsigned long long)out_size;

    if (n_in != 10) {
        Net_49976239456390_kernel<<<1024, 256, 0, stream>>>(out, on, 55.f);
        return;
    }
    if (in_sizes[0] != BDIM * XDIM || in_sizes[3] != IDIM * DDIM || in_sizes[9] != DDIM) {
        Net_49976239456390_kernel<<<1024, 256, 0, stream>>>(out, on, 66.f);
        return;
    }
    // single-chunk layout: h1 [B][I] fp32 (128 MB) + h2 [B][D] fp32 (256 MB)
    const size_t need = (size_t)BDIM * IDIM * 4 + (size_t)BDIM * DDIM * 4;
    if (need > ws_size) {
        Net_49976239456390_kernel<<<1024, 256, 0, stream>>>(out, on, 99.f);
        return;
    }

    Net_49976239456390_kernel<<<1024, 256, 0, stream>>>(out, on, 7.f);

    const float* x   = (const float*)d_in[0];
    const float* W1  = (const float*)d_in[1];
    const float* b1  = (const float*)d_in[2];
    const float* W2  = (const float*)d_in[3];
    const float* b2  = (const float*)d_in[4];
    const float* W3  = (const float*)d_in[5];
    const float* b3  = (const float*)d_in[6];
    const float* W4  = (const float*)d_in[7];
    const float* b4  = (const float*)d_in[8];
    const float* bsc = (const float*)d_in[9];

    float* h1 = (float*)d_ws;                     // [B][I], reused as h3
    float* h2 = h1 + (size_t)BDIM * IDIM;         // [B][D], flat in place

    dim3 blk(256);
    gemm_relu<<<dim3(IDIM / 128, BDIM / 128), blk, 0, stream>>>(
        x, W1, b1, h1, IDIM, XDIM);
    gemm2_split<<<dim3(DDIM / 128, BDIM / 128), blk, 0, stream>>>(
        h1, W2, b2, h2);
    kwinner_stripes<<<dim3(BDIM), blk, 0, stream>>>(h2, bsc);
    gemm_v2split<<<dim3(IDIM / 128, BDIM / 128), blk, 0, stream>>>(
        h2, W3, b3, h1, IDIM, DDIM);
    gemm_v2split<<<dim3((XDIM + 127) / 128, BDIM / 128), blk, 0, stream>>>(
        h1, W4, b4, out, XDIM, IDIM);
}

// Round 11
// 6878.590 us; speedup vs baseline: 1.3386x; 1.0170x over previous
//
#include <hip/hip_runtime.h>
#include <hip/hip_bf16.h>

// ---------------------------------------------------------------------------
// Net_49976239456390 — Round 11: evidence-based revert of round-10's two
// regressions, keeping its one win.
//   - REVERT LDS swizzle (made conflicts worse: 16B-granule XOR over 16B-
//     multiple strides only permutes collisions; broke free 2-way pairs)
//   - REVERT af-reads-in-loop: hoist af[3][4] (24 ds_read_b128/wave-iter,
//     round-7 pattern) — LDS pipe is the contended resource
//   - KEEP truncation splits (VALU win)
//   - ADD register prefetch: next tile's global loads issued right after
//     current staging writes -> latency hidden under transpose+MFMA
// ---------------------------------------------------------------------------

#define BDIM 8192
#define IDIM 4096
#define DDIM 8192
#define XDIM 784
#define KNEUR 512
#define KSTR  16

typedef __attribute__((ext_vector_type(8))) short bf16x8;
typedef __attribute__((ext_vector_type(4))) float f32x4;

#define LDT 40            // padded LDS row: 40 shorts = 80 B
#define PT  (128 * LDT)   // one plane tile in shorts

// identifier-named kernel: grid-stride fp32 fill (sentinel / error codes)
__global__ void Net_49976239456390_kernel(float* out, unsigned long long n, float v)
{
    unsigned long long i = (unsigned long long)blockIdx.x * blockDim.x + threadIdx.x;
    unsigned long long step = (unsigned long long)gridDim.x * blockDim.x;
    for (; i < n; i += step) out[i] = v;
}

// ---- exact truncation splits (packed pairs, little-endian short order) ------
__device__ __forceinline__ void tsplit3_pair(float f0, float f1,
                                             unsigned& w0, unsigned& w1, unsigned& w2)
{
    unsigned u0 = __float_as_uint(f0), u1 = __float_as_uint(f1);
    unsigned h0 = u0 & 0xFFFF0000u,  h1 = u1 & 0xFFFF0000u;
    float r0 = f0 - __uint_as_float(h0);
    float r1 = f1 - __uint_as_float(h1);
    unsigned v0 = __float_as_uint(r0) & 0xFFFF0000u;
    unsigned v1 = __float_as_uint(r1) & 0xFFFF0000u;
    float s0 = r0 - __uint_as_float(v0);
    float s1 = r1 - __uint_as_float(v1);
    w0 = (h0 >> 16) | h1;
    w1 = (v0 >> 16) | v1;
    w2 = (__float_as_uint(s0) >> 16) | (__float_as_uint(s1) & 0xFFFF0000u);
}

__device__ __forceinline__ void tsplit2_pair(float f0, float f1,
                                             unsigned& w0, unsigned& w1)
{
    unsigned u0 = __float_as_uint(f0), u1 = __float_as_uint(f1);
    unsigned h0 = u0 & 0xFFFF0000u,  h1 = u1 & 0xFFFF0000u;
    float r0 = f0 - __uint_as_float(h0);
    float r1 = f1 - __uint_as_float(h1);
    w0 = (h0 >> 16) | h1;
    w1 = (__float_as_uint(r0) >> 16) | (__float_as_uint(r1) & 0xFFFF0000u);
}

// ---- fp32 GEMM: C = relu(A @ B + bias) (GEMM1) ------------------------------
__global__ __launch_bounds__(256)
void gemm_relu(const float* A, const float* B, const float* bias, float* C,
               int N, int K)
{
    __shared__ float as[8][128];
    __shared__ float bs[8][128];

    const int tid = threadIdx.x;
    const int bm = blockIdx.y * 128;
    const int bn = blockIdx.x * 128;
    const int tx = tid & 15, ty = tid >> 4;
    const int r0 = ty * 4, c0 = tx * 4;
    const int a_m = tid >> 1, a_k = (tid & 1) * 4;
    const int b_k = tid >> 5, b_n = (tid & 31) * 4;

    const float* Ap = A + (size_t)(bm + a_m) * K + a_k;
    const float* Bp = B + (size_t)b_k * N + (bn + b_n);
    const bool bok = (bn + b_n + 3 < N);

    float acc[8][8];
#pragma unroll
    for (int i = 0; i < 8; ++i)
#pragma unroll
        for (int j = 0; j < 8; ++j) acc[i][j] = 0.f;

    for (int k0 = 0; k0 < K; k0 += 8) {
        float4 av = *(const float4*)(Ap + k0);
        float4 bv = make_float4(0.f, 0.f, 0.f, 0.f);
        if (bok) bv = *(const float4*)(Bp + (size_t)k0 * N);
        __syncthreads();
        as[a_k + 0][a_m] = av.x;
        as[a_k + 1][a_m] = av.y;
        as[a_k + 2][a_m] = av.z;
        as[a_k + 3][a_m] = av.w;
        *(float4*)&bs[b_k][b_n] = bv;
        __syncthreads();
#pragma unroll
        for (int k = 0; k < 8; ++k) {
            float4 a0 = *(const float4*)&as[k][r0];
            float4 a1 = *(const float4*)&as[k][r0 + 64];
            float4 b0 = *(const float4*)&bs[k][c0];
            float4 b1 = *(const float4*)&bs[k][c0 + 64];
            float aa[8] = {a0.x, a0.y, a0.z, a0.w, a1.x, a1.y, a1.z, a1.w};
            float bb[8] = {b0.x, b0.y, b0.z, b0.w, b1.x, b1.y, b1.z, b1.w};
#pragma unroll
            for (int i = 0; i < 8; ++i)
#pragma unroll
                for (int j = 0; j < 8; ++j)
                    acc[i][j] = fmaf(aa[i], bb[j], acc[i][j]);
        }
    }

#pragma unroll
    for (int i = 0; i < 8; ++i) {
        const int rr = bm + r0 + ((i >> 2) << 6) + (i & 3);
        float* op = C + (size_t)rr * N;
#pragma unroll
        for (int j = 0; j < 8; ++j) {
            int cc = bn + c0 + ((j >> 2) << 6) + (j & 3);
            if (cc < N)
                op[cc] = fmaxf(acc[i][j] + bias[cc], 0.f);
        }
    }
}

// ---- GEMM2: h2 = relu(h1 @ W2 + b2), 3-term split, 6 products ---------------
__global__ __launch_bounds__(256, 2)
void gemm2_split(const float* __restrict__ A, const float* __restrict__ B,
                 const float* __restrict__ bias, float* __restrict__ C)
{
    __shared__ short as[3 * PT];
    __shared__ short bs[3 * PT];
    __shared__ float bsrc[32 * 128];

    const int tid = threadIdx.x;
    const int lane = tid & 63;
    const int wid = tid >> 6;
    const int wr = (wid >> 1) * 64;
    const int wc = (wid & 1) * 64;
    const int l15 = lane & 15;
    const int lk8 = (lane >> 4) * 8;
    const int bm = blockIdx.y * 128;
    const int bn = blockIdx.x * 128;
    const int tn = tid & 127;
    const int tkh = (tid >> 7) * 16;

    // loop-invariant addresses
    const float* a_src[4];
    int a_soff[4];
#pragma unroll
    for (int p = 0; p < 4; ++p) {
        int idx = p * 256 + tid;
        int m = idx >> 3;
        int kf = (idx & 7) << 2;
        a_src[p] = A + (size_t)(bm + m) * IDIM + kf;
        a_soff[p] = m * LDT + kf;
    }
    const int b_k = tid >> 5;
    const int b_n = (tid & 31) * 4;
    const float* b_src[4];
#pragma unroll
    for (int p = 0; p < 4; ++p)
        b_src[p] = B + (size_t)(p * 8 + b_k) * DDIM + bn + b_n;
    int aoff[4], boff[4];
#pragma unroll
    for (int mi = 0; mi < 4; ++mi) aoff[mi] = (wr + mi * 16 + l15) * LDT + lk8;
#pragma unroll
    for (int ni = 0; ni < 4; ++ni) boff[ni] = (wc + ni * 16 + l15) * LDT + lk8;

    f32x4 accM[4][4];
    f32x4 accR[4][4];
#pragma unroll
    for (int i = 0; i < 4; ++i)
#pragma unroll
        for (int j = 0; j < 4; ++j) {
            accM[i][j] = (f32x4){0.f, 0.f, 0.f, 0.f};
            accR[i][j] = (f32x4){0.f, 0.f, 0.f, 0.f};
        }

    // prologue loads (tile 0)
    float4 avr[4], bvr[4];
#pragma unroll
    for (int p = 0; p < 4; ++p) avr[p] = *(const float4*)(a_src[p]);
#pragma unroll
    for (int p = 0; p < 4; ++p) bvr[p] = *(const float4*)(b_src[p]);

    for (int k0 = 0; k0 < IDIM; k0 += 32) {
        __syncthreads();   // prior iter's frag + bsrc reads done
        // stage A (split) + B raw
#pragma unroll
        for (int p = 0; p < 4; ++p) {
            unsigned w0a, w1a, w2a, w0b, w1b, w2b;
            tsplit3_pair(avr[p].x, avr[p].y, w0a, w1a, w2a);
            tsplit3_pair(avr[p].z, avr[p].w, w0b, w1b, w2b);
            *(uint2*)&as[a_soff[p]]          = make_uint2(w0a, w0b);
            *(uint2*)&as[PT + a_soff[p]]     = make_uint2(w1a, w1b);
            *(uint2*)&as[2 * PT + a_soff[p]] = make_uint2(w2a, w2b);
        }
#pragma unroll
        for (int p = 0; p < 4; ++p)
            *(float4*)&bsrc[(p * 8 + b_k) * 128 + b_n] = bvr[p];

        // prefetch next tile (in flight over transpose + MFMA)
        int kn = k0 + 32;
        if (kn < IDIM) {
#pragma unroll
            for (int p = 0; p < 4; ++p) avr[p] = *(const float4*)(a_src[p] + kn);
#pragma unroll
            for (int p = 0; p < 4; ++p) bvr[p] = *(const float4*)(b_src[p] + (size_t)kn * DDIM);
        }
        __syncthreads();   // bsrc + as ready

        // transpose + split -> bs planes
#pragma unroll
        for (int q = 0; q < 4; ++q) {
            int kq = tkh + q * 4;
            float f0 = bsrc[(kq + 0) * 128 + tn];
            float f1 = bsrc[(kq + 1) * 128 + tn];
            float f2 = bsrc[(kq + 2) * 128 + tn];
            float f3 = bsrc[(kq + 3) * 128 + tn];
            unsigned w0a, w1a, w2a, w0b, w1b, w2b;
            tsplit3_pair(f0, f1, w0a, w1a, w2a);
            tsplit3_pair(f2, f3, w0b, w1b, w2b);
            int off = tn * LDT + kq;
            *(uint2*)&bs[off]          = make_uint2(w0a, w0b);
            *(uint2*)&bs[PT + off]     = make_uint2(w1a, w1b);
            *(uint2*)&bs[2 * PT + off] = make_uint2(w2a, w2b);
        }
        __syncthreads();   // bs ready

        // hoisted A frags (12 reads), then per-q B frags (12 reads)
        bf16x8 af[3][4];
#pragma unroll
        for (int p = 0; p < 3; ++p)
#pragma unroll
            for (int mi = 0; mi < 4; ++mi)
                af[p][mi] = *(const bf16x8*)&as[p * PT + aoff[mi]];

#pragma unroll
        for (int q = 0; q < 3; ++q) {
            bf16x8 bf[4];
#pragma unroll
            for (int ni = 0; ni < 4; ++ni)
                bf[ni] = *(const bf16x8*)&bs[q * PT + boff[ni]];
#pragma unroll
            for (int p = 0; p < 3; ++p) {
                if (p + q > 2) continue;
                if (p == 0 && q == 0) {
#pragma unroll
                    for (int mi = 0; mi < 4; ++mi)
#pragma unroll
                        for (int ni = 0; ni < 4; ++ni)
                            accM[mi][ni] = __builtin_amdgcn_mfma_f32_16x16x32_bf16(
                                af[0][mi], bf[ni], accM[mi][ni], 0, 0, 0);
                } else {
#pragma unroll
                    for (int mi = 0; mi < 4; ++mi)
#pragma unroll
                        for (int ni = 0; ni < 4; ++ni)
                            accR[mi][ni] = __builtin_amdgcn_mfma_f32_16x16x32_bf16(
                                af[p][mi], bf[ni], accR[mi][ni], 0, 0, 0);
                }
            }
        }
    }

    const int rsub = (lane >> 4) * 4;
#pragma unroll
    for (int mi = 0; mi < 4; ++mi) {
        int row0 = bm + wr + mi * 16 + rsub;
#pragma unroll
        for (int ni = 0; ni < 4; ++ni) {
            int col = bn + wc + ni * 16 + l15;
            float bb = bias[col];
#pragma unroll
            for (int r = 0; r < 4; ++r) {
                float s = accR[mi][ni][r] + accM[mi][ni][r];
                C[(size_t)(row0 + r) * DDIM + col] = fmaxf(s + bb, 0.f);
            }
        }
    }
}

// ---- value-only split GEMM: 2-term, 3 products (GEMM3 and GEMM4) ------------
__global__ __launch_bounds__(256, 2)
void gemm_v2split(const float* __restrict__ A, const float* __restrict__ B,
                  const float* __restrict__ bias, float* __restrict__ C,
                  int N, int K)
{
    __shared__ short as[2 * PT];
    __shared__ short bs[2 * PT];
    __shared__ float bsrc[32 * 128];

    const int tid = threadIdx.x;
    const int lane = tid & 63;
    const int wid = tid >> 6;
    const int wr = (wid >> 1) * 64;
    const int wc = (wid & 1) * 64;
    const int l15 = lane & 15;
    const int lk8 = (lane >> 4) * 8;
    const int bm = blockIdx.y * 128;
    const int bn = blockIdx.x * 128;
    const int tn = tid & 127;
    const int tkh = (tid >> 7) * 16;

    const float* a_src[4];
    int a_soff[4];
#pragma unroll
    for (int p = 0; p < 4; ++p) {
        int idx = p * 256 + tid;
        int m = idx >> 3;
        int kf = (idx & 7) << 2;
        a_src[p] = A + (size_t)(bm + m) * K + kf;
        a_soff[p] = m * LDT + kf;
    }
    const int b_k = tid >> 5;
    const int b_n = (tid & 31) * 4;
    const bool bok = (bn + b_n + 3 < N);
    const float* b_src[4];
#pragma unroll
    for (int p = 0; p < 4; ++p)
        b_src[p] = B + (size_t)(p * 8 + b_k) * N + bn + b_n;
    int aoff[4], boff[4];
#pragma unroll
    for (int mi = 0; mi < 4; ++mi) aoff[mi] = (wr + mi * 16 + l15) * LDT + lk8;
#pragma unroll
    for (int ni = 0; ni < 4; ++ni) boff[ni] = (wc + ni * 16 + l15) * LDT + lk8;

    f32x4 accM[4][4];
    f32x4 accR[4][4];
#pragma unroll
    for (int i = 0; i < 4; ++i)
#pragma unroll
        for (int j = 0; j < 4; ++j) {
            accM[i][j] = (f32x4){0.f, 0.f, 0.f, 0.f};
            accR[i][j] = (f32x4){0.f, 0.f, 0.f, 0.f};
        }

    float4 avr[4], bvr[4];
#pragma unroll
    for (int p = 0; p < 4; ++p) avr[p] = *(const float4*)(a_src[p]);
#pragma unroll
    for (int p = 0; p < 4; ++p)
        bvr[p] = bok ? *(const float4*)(b_src[p]) : make_float4(0.f, 0.f, 0.f, 0.f);

    for (int k0 = 0; k0 < K; k0 += 32) {
        __syncthreads();
#pragma unroll
        for (int p = 0; p < 4; ++p) {
            unsigned w0a, w1a, w0b, w1b;
            tsplit2_pair(avr[p].x, avr[p].y, w0a, w1a);
            tsplit2_pair(avr[p].z, avr[p].w, w0b, w1b);
            *(uint2*)&as[a_soff[p]]      = make_uint2(w0a, w0b);
            *(uint2*)&as[PT + a_soff[p]] = make_uint2(w1a, w1b);
        }
#pragma unroll
        for (int p = 0; p < 4; ++p)
            *(float4*)&bsrc[(p * 8 + b_k) * 128 + b_n] = bvr[p];

        int kn = k0 + 32;
        if (kn < K) {
#pragma unroll
            for (int p = 0; p < 4; ++p) avr[p] = *(const float4*)(a_src[p] + kn);
#pragma unroll
            for (int p = 0; p < 4; ++p)
                bvr[p] = bok ? *(const float4*)(b_src[p] + (size_t)kn * N)
                             : make_float4(0.f, 0.f, 0.f, 0.f);
        }
        __syncthreads();

#pragma unroll
        for (int q = 0; q < 4; ++q) {
            int kq = tkh + q * 4;
            float f0 = bsrc[(kq + 0) * 128 + tn];
            float f1 = bsrc[(kq + 1) * 128 + tn];
            float f2 = bsrc[(kq + 2) * 128 + tn];
            float f3 = bsrc[(kq + 3) * 128 + tn];
            unsigned w0a, w1a, w0b, w1b;
            tsplit2_pair(f0, f1, w0a, w1a);
            tsplit2_pair(f2, f3, w0b, w1b);
            int off = tn * LDT + kq;
            *(uint2*)&bs[off]      = make_uint2(w0a, w0b);
            *(uint2*)&bs[PT + off] = make_uint2(w1a, w1b);
        }
        __syncthreads();

        bf16x8 af[2][4];
#pragma unroll
        for (int p = 0; p < 2; ++p)
#pragma unroll
            for (int mi = 0; mi < 4; ++mi)
                af[p][mi] = *(const bf16x8*)&as[p * PT + aoff[mi]];

#pragma unroll
        for (int q = 0; q < 2; ++q) {
            bf16x8 bf[4];
#pragma unroll
            for (int ni = 0; ni < 4; ++ni)
                bf[ni] = *(const bf16x8*)&bs[q * PT + boff[ni]];
#pragma unroll
            for (int p = 0; p < 2; ++p) {
                if (p + q > 1) continue;
                if (p == 0 && q == 0) {
#pragma unroll
                    for (int mi = 0; mi < 4; ++mi)
#pragma unroll
                        for (int ni = 0; ni < 4; ++ni)
                            accM[mi][ni] = __builtin_amdgcn_mfma_f32_16x16x32_bf16(
                                af[0][mi], bf[ni], accM[mi][ni], 0, 0, 0);
                } else {
#pragma unroll
                    for (int mi = 0; mi < 4; ++mi)
#pragma unroll
                        for (int ni = 0; ni < 4; ++ni)
                            accR[mi][ni] = __builtin_amdgcn_mfma_f32_16x16x32_bf16(
                                af[p][mi], bf[ni], accR[mi][ni], 0, 0, 0);
                }
            }
        }
    }

    const int rsub = (lane >> 4) * 4;
#pragma unroll
    for (int mi = 0; mi < 4; ++mi) {
        int row0 = bm + wr + mi * 16 + rsub;
#pragma unroll
        for (int ni = 0; ni < 4; ++ni) {
            int col = bn + wc + ni * 16 + l15;
            if (col < N) {
                float bb = bias[col];
#pragma unroll
                for (int r = 0; r < 4; ++r) {
                    float s = accR[mi][ni][r] + accM[mi][ni][r];
                    C[(size_t)(row0 + r) * N + col] = fmaxf(s + bb, 0.f);
                }
            }
        }
    }
}

// ---- k-winner (exact top-512, radix on fp32 bits, jax leftmost ties) -------
__global__ __launch_bounds__(256)
void kwinner_stripes(float* h2, const float* bscores)
{
    const int row = blockIdx.x;
    const int tid = threadIdx.x;
    float* rowp = h2 + (size_t)row * DDIM;

    __shared__ float  mv[DDIM];
    __shared__ int    ired[256];
    __shared__ double dred[256];
    __shared__ int    warr[4];
    __shared__ double ssum[128];
    __shared__ float  smk[128];

#pragma unroll
    for (int i = 0; i < 32; ++i) {
        int j = tid + i * 256;
        mv[j] = expf(0.0f - bscores[j]) * rowp[j];   // BETA=1, GAMMA=0
    }
    __syncthreads();

    unsigned t = 0;
    for (int bit = 30; bit >= 0; --bit) {
        unsigned cand = t | (1u << bit);
        int cnt = 0;
#pragma unroll
        for (int i = 0; i < 32; ++i)
            cnt += (__float_as_uint(mv[tid + i * 256]) >= cand) ? 1 : 0;
        for (int off = 32; off; off >>= 1) cnt += __shfl_down(cnt, off);
        if ((tid & 63) == 0) warr[tid >> 6] = cnt;
        __syncthreads();
        int tot = warr[0] + warr[1] + warr[2] + warr[3];
        __syncthreads();
        if (tot >= KNEUR) t = cand;
    }
    {
        int cnt = 0;
#pragma unroll
        for (int i = 0; i < 32; ++i)
            cnt += (__float_as_uint(mv[tid + i * 256]) > t) ? 1 : 0;
        for (int off = 32; off; off >>= 1) cnt += __shfl_down(cnt, off);
        if ((tid & 63) == 0) warr[tid >> 6] = cnt;
        __syncthreads();
    }
    const int need_eq = KNEUR - (warr[0] + warr[1] + warr[2] + warr[3]);
    __syncthreads();

    const int base = tid * 32;
    int myeq = 0;
#pragma unroll
    for (int i = 0; i < 32; ++i)
        myeq += (__float_as_uint(mv[base + i]) == t) ? 1 : 0;
    int val = myeq;
    ired[tid] = val;
    __syncthreads();
    for (int s = 1; s < 256; s <<= 1) {
        int add = (tid >= s) ? ired[tid - s] : 0;
        __syncthreads();
        val += add;
        ired[tid] = val;
        __syncthreads();
    }
    const int before = val - myeq;

    double partial = 0.0;
    int eqseen = 0;
#pragma unroll
    for (int i = 0; i < 32; ++i) {
        int j = base + i;
        float m = mv[j];
        unsigned u = __float_as_uint(m);
        bool sel = (u > t) || (u == t && (before + eqseen) < need_eq);
        if (u == t) ++eqseen;
        float code = sel ? m * rowp[j] : 0.f;
        mv[j] = code;
        partial += (double)code;
    }
    dred[tid] = partial;
    __syncthreads();
    if (tid < 128) ssum[tid] = dred[2 * tid] + dred[2 * tid + 1];
    __syncthreads();

    if (tid < 128) {
        double v = ssum[tid];
        int rank = 0;
        for (int j = 0; j < 128; ++j) {
            double w = ssum[j];
            rank += (w > v) ? 1 : 0;
            rank += (w == v && j < tid) ? 1 : 0;
        }
        smk[tid] = (rank < KSTR) ? 1.f : 0.f;
    }
    __syncthreads();

#pragma unroll
    for (int i = 0; i < 32; ++i) {
        int j = tid + i * 256;
        rowp[j] = mv[j] * smk[j >> 6];
    }
}

// ---------------------------------------------------------------------------
extern "C" void kernel_launch(void* const* d_in, const int* in_sizes, int n_in,
                              void* d_out, int out_size, void* d_ws, size_t ws_size,
                              hipStream_t stream)
{
    float* out = (float*)d_out;
    const unsigned long long on = (unsigned long long)out_size;

    if (n_in != 10) {
        Net_49976239456390_kernel<<<1024, 256, 0, stream>>>(out, on, 55.f);
        return;
    }
    if (in_sizes[0] != BDIM * XDIM || in_sizes[3] != IDIM * DDIM || in_sizes[9] != DDIM) {
        Net_49976239456390_kernel<<<1024, 256, 0, stream>>>(out, on, 66.f);
        return;
    }
    const size_t need = (size_t)BDIM * IDIM * 4 + (size_t)BDIM * DDIM * 4;
    if (need > ws_size) {
        Net_49976239456390_kernel<<<1024, 256, 0, stream>>>(out, on, 99.f);
        return;
    }

    Net_49976239456390_kernel<<<1024, 256, 0, stream>>>(out, on, 7.f);

    const float* x   = (const float*)d_in[0];
    const float* W1  = (const float*)d_in[1];
    const float* b1  = (const float*)d_in[2];
    const float* W2  = (const float*)d_in[3];
    const float* b2  = (const float*)d_in[4];
    const float* W3  = (const float*)d_in[5];
    const float* b3  = (const float*)d_in[6];
    const float* W4  = (const float*)d_in[7];
    const float* b4  = (const float*)d_in[8];
    const float* bsc = (const float*)d_in[9];

    float* h1 = (float*)d_ws;                     // [B][I], reused as h3
    float* h2 = h1 + (size_t)BDIM * IDIM;         // [B][D], flat in place

    dim3 blk(256);
    gemm_relu<<<dim3(IDIM / 128, BDIM / 128), blk, 0, stream>>>(
        x, W1, b1, h1, IDIM, XDIM);
    gemm2_split<<<dim3(DDIM / 128, BDIM / 128), blk, 0, stream>>>(
        h1, W2, b2, h2);
    kwinner_stripes<<<dim3(BDIM), blk, 0, stream>>>(h2, bsc);
    gemm_v2split<<<dim3(IDIM / 128, BDIM / 128), blk, 0, stream>>>(
        h2, W3, b3, h1, IDIM, DDIM);
    gemm_v2split<<<dim3((XDIM + 127) / 128, BDIM / 128), blk, 0, stream>>>(
        h1, W4, b4, out, XDIM, IDIM);
}

// Round 12
// 6106.718 us; speedup vs baseline: 1.5077x; 1.1264x over previous
//
#include <hip/hip_runtime.h>
#include <hip/hip_bf16.h>

// ---------------------------------------------------------------------------
// Net_49976239456390 — Round 12: recombination of best measured kernels.
//   - gemm2_split: EXACT round-7 code (3.5 ms, 46% MfmaUtil, 262 MB writes).
//     r10/r11 variants (trunc split / prefetch) regressed it to 4.2-4.5 ms
//     with 1.3-2.0 GB write amplification — reverted wholesale.
//   - gemm3/gemm4: round-11 gemm_v2split (trunc split + prefetch, 2 planes)
//     — measured ~1.0 ms faster combined than the r7 equivalents.
//   - gemm1, kwinner, launcher unchanged.
// ---------------------------------------------------------------------------

#define BDIM 8192
#define IDIM 4096
#define DDIM 8192
#define XDIM 784
#define KNEUR 512
#define KSTR  16

typedef __attribute__((ext_vector_type(8))) short bf16x8;
typedef __attribute__((ext_vector_type(4))) float f32x4;

#define LDT 40            // padded LDS row: 40 shorts = 80 B
#define PT  (128 * LDT)   // one plane tile in shorts

// identifier-named kernel: grid-stride fp32 fill (sentinel / error codes)
__global__ void Net_49976239456390_kernel(float* out, unsigned long long n, float v)
{
    unsigned long long i = (unsigned long long)blockIdx.x * blockDim.x + threadIdx.x;
    unsigned long long step = (unsigned long long)gridDim.x * blockDim.x;
    for (; i < n; i += step) out[i] = v;
}

// ---- RNE 3-term split (round-7 gemm2 path) ----------------------------------
__device__ __forceinline__ void split3(float f, short& s0, short& s1, short& s2)
{
    __hip_bfloat16 b0 = __float2bfloat16(f);
    float r1 = f - __bfloat162float(b0);
    __hip_bfloat16 b1 = __float2bfloat16(r1);
    float r2 = r1 - __bfloat162float(b1);
    __hip_bfloat16 b2 = __float2bfloat16(r2);
    s0 = *(short*)&b0; s1 = *(short*)&b1; s2 = *(short*)&b2;
}

// ---- truncation 2-term split, packed pair (round-11 v2split path) ----------
__device__ __forceinline__ void tsplit2_pair(float f0, float f1,
                                             unsigned& w0, unsigned& w1)
{
    unsigned u0 = __float_as_uint(f0), u1 = __float_as_uint(f1);
    unsigned h0 = u0 & 0xFFFF0000u,  h1 = u1 & 0xFFFF0000u;
    float r0 = f0 - __uint_as_float(h0);
    float r1 = f1 - __uint_as_float(h1);
    w0 = (h0 >> 16) | h1;
    w1 = (__float_as_uint(r0) >> 16) | (__float_as_uint(r1) & 0xFFFF0000u);
}

// ---- fp32 GEMM: C = relu(A @ B + bias) (GEMM1) ------------------------------
__global__ __launch_bounds__(256)
void gemm_relu(const float* A, const float* B, const float* bias, float* C,
               int N, int K)
{
    __shared__ float as[8][128];
    __shared__ float bs[8][128];

    const int tid = threadIdx.x;
    const int bm = blockIdx.y * 128;
    const int bn = blockIdx.x * 128;
    const int tx = tid & 15, ty = tid >> 4;
    const int r0 = ty * 4, c0 = tx * 4;
    const int a_m = tid >> 1, a_k = (tid & 1) * 4;
    const int b_k = tid >> 5, b_n = (tid & 31) * 4;

    const float* Ap = A + (size_t)(bm + a_m) * K + a_k;
    const float* Bp = B + (size_t)b_k * N + (bn + b_n);
    const bool bok = (bn + b_n + 3 < N);

    float acc[8][8];
#pragma unroll
    for (int i = 0; i < 8; ++i)
#pragma unroll
        for (int j = 0; j < 8; ++j) acc[i][j] = 0.f;

    for (int k0 = 0; k0 < K; k0 += 8) {
        float4 av = *(const float4*)(Ap + k0);
        float4 bv = make_float4(0.f, 0.f, 0.f, 0.f);
        if (bok) bv = *(const float4*)(Bp + (size_t)k0 * N);
        __syncthreads();
        as[a_k + 0][a_m] = av.x;
        as[a_k + 1][a_m] = av.y;
        as[a_k + 2][a_m] = av.z;
        as[a_k + 3][a_m] = av.w;
        *(float4*)&bs[b_k][b_n] = bv;
        __syncthreads();
#pragma unroll
        for (int k = 0; k < 8; ++k) {
            float4 a0 = *(const float4*)&as[k][r0];
            float4 a1 = *(const float4*)&as[k][r0 + 64];
            float4 b0 = *(const float4*)&bs[k][c0];
            float4 b1 = *(const float4*)&bs[k][c0 + 64];
            float aa[8] = {a0.x, a0.y, a0.z, a0.w, a1.x, a1.y, a1.z, a1.w};
            float bb[8] = {b0.x, b0.y, b0.z, b0.w, b1.x, b1.y, b1.z, b1.w};
#pragma unroll
            for (int i = 0; i < 8; ++i)
#pragma unroll
                for (int j = 0; j < 8; ++j)
                    acc[i][j] = fmaf(aa[i], bb[j], acc[i][j]);
        }
    }

#pragma unroll
    for (int i = 0; i < 8; ++i) {
        const int rr = bm + r0 + ((i >> 2) << 6) + (i & 3);
        float* op = C + (size_t)rr * N;
#pragma unroll
        for (int j = 0; j < 8; ++j) {
            int cc = bn + c0 + ((j >> 2) << 6) + (j & 3);
            if (cc < N)
                op[cc] = fmaxf(acc[i][j] + bias[cc], 0.f);
        }
    }
}

// ---- GEMM2: h2 = relu(h1 @ W2 + b2), 3-term split, 6 products ---------------
// EXACT round-7 structure (proven 3.5 ms / MfmaUtil 46%).
__global__ __launch_bounds__(256, 2)
void gemm2_split(const float* __restrict__ A, const float* __restrict__ B,
                 const float* __restrict__ bias, float* __restrict__ C)
{
    __shared__ short as[3][128 * LDT];
    __shared__ short bs[3][128 * LDT];
    __shared__ float bsrc[32 * 128];

    const int tid = threadIdx.x;
    const int lane = tid & 63;
    const int wid = tid >> 6;
    const int wr = (wid >> 1) * 64;
    const int wc = (wid & 1) * 64;
    const int l15 = lane & 15;
    const int lk8 = (lane >> 4) * 8;
    const int bm = blockIdx.y * 128;
    const int bn = blockIdx.x * 128;

    const int tn = tid & 127;
    const int tkh = (tid >> 7) * 16;

    f32x4 accM[4][4];
    f32x4 accR[4][4];
#pragma unroll
    for (int i = 0; i < 4; ++i)
#pragma unroll
        for (int j = 0; j < 4; ++j) {
            accM[i][j] = (f32x4){0.f, 0.f, 0.f, 0.f};
            accR[i][j] = (f32x4){0.f, 0.f, 0.f, 0.f};
        }

    for (int k0 = 0; k0 < IDIM; k0 += 32) {
        __syncthreads();

#pragma unroll
        for (int pass = 0; pass < 4; ++pass) {
            int idx = pass * 256 + tid;
            int m = idx >> 3;
            int kf = (idx & 7) << 2;
            float4 v = *(const float4*)(A + (size_t)(bm + m) * IDIM + k0 + kf);
            short s0[4], s1[4], s2[4];
            split3(v.x, s0[0], s1[0], s2[0]);
            split3(v.y, s0[1], s1[1], s2[1]);
            split3(v.z, s0[2], s1[2], s2[2]);
            split3(v.w, s0[3], s1[3], s2[3]);
            int off = m * LDT + kf;
            *(short4*)&as[0][off] = make_short4(s0[0], s0[1], s0[2], s0[3]);
            *(short4*)&as[1][off] = make_short4(s1[0], s1[1], s1[2], s1[3]);
            *(short4*)&as[2][off] = make_short4(s2[0], s2[1], s2[2], s2[3]);
        }
#pragma unroll
        for (int pass = 0; pass < 4; ++pass) {
            int idx = pass * 256 + tid;
            int k = idx >> 5;
            int nf = (idx & 31) << 2;
            float4 v = *(const float4*)(B + (size_t)(k0 + k) * DDIM + bn + nf);
            *(float4*)&bsrc[k * 128 + nf] = v;
        }
        __syncthreads();

#pragma unroll
        for (int q = 0; q < 4; ++q) {
            int kq = tkh + q * 4;
            short s0[4], s1[4], s2[4];
#pragma unroll
            for (int e = 0; e < 4; ++e) {
                float f = bsrc[(kq + e) * 128 + tn];
                split3(f, s0[e], s1[e], s2[e]);
            }
            int off = tn * LDT + kq;
            *(short4*)&bs[0][off] = make_short4(s0[0], s0[1], s0[2], s0[3]);
            *(short4*)&bs[1][off] = make_short4(s1[0], s1[1], s1[2], s1[3]);
            *(short4*)&bs[2][off] = make_short4(s2[0], s2[1], s2[2], s2[3]);
        }
        __syncthreads();

        bf16x8 af[3][4];
#pragma unroll
        for (int p = 0; p < 3; ++p)
#pragma unroll
            for (int mi = 0; mi < 4; ++mi)
                af[p][mi] = *(const bf16x8*)&as[p][(wr + mi * 16 + l15) * LDT + lk8];

#pragma unroll
        for (int q = 0; q < 3; ++q) {
            bf16x8 bf[4];
#pragma unroll
            for (int ni = 0; ni < 4; ++ni)
                bf[ni] = *(const bf16x8*)&bs[q][(wc + ni * 16 + l15) * LDT + lk8];
#pragma unroll
            for (int p = 0; p < 3; ++p) {
                if (p + q > 2) continue;
                if (p == 0 && q == 0) {
#pragma unroll
                    for (int mi = 0; mi < 4; ++mi)
#pragma unroll
                        for (int ni = 0; ni < 4; ++ni)
                            accM[mi][ni] = __builtin_amdgcn_mfma_f32_16x16x32_bf16(
                                af[0][mi], bf[ni], accM[mi][ni], 0, 0, 0);
                } else {
#pragma unroll
                    for (int mi = 0; mi < 4; ++mi)
#pragma unroll
                        for (int ni = 0; ni < 4; ++ni)
                            accR[mi][ni] = __builtin_amdgcn_mfma_f32_16x16x32_bf16(
                                af[p][mi], bf[ni], accR[mi][ni], 0, 0, 0);
                }
            }
        }
    }

    const int rsub = (lane >> 4) * 4;
#pragma unroll
    for (int mi = 0; mi < 4; ++mi) {
        int row0 = bm + wr + mi * 16 + rsub;
#pragma unroll
        for (int ni = 0; ni < 4; ++ni) {
            int col = bn + wc + ni * 16 + l15;
            float bb = bias[col];
#pragma unroll
            for (int r = 0; r < 4; ++r) {
                float s = accR[mi][ni][r] + accM[mi][ni][r];
                C[(size_t)(row0 + r) * DDIM + col] = fmaxf(s + bb, 0.f);
            }
        }
    }
}

// ---- value-only split GEMM: 2-term, 3 products (GEMM3 and GEMM4) ------------
// EXACT round-11 code (measured ~1.0 ms faster combined than r7 equivalents).
__global__ __launch_bounds__(256, 2)
void gemm_v2split(const float* __restrict__ A, const float* __restrict__ B,
                  const float* __restrict__ bias, float* __restrict__ C,
                  int N, int K)
{
    __shared__ short as[2 * PT];
    __shared__ short bs[2 * PT];
    __shared__ float bsrc[32 * 128];

    const int tid = threadIdx.x;
    const int lane = tid & 63;
    const int wid = tid >> 6;
    const int wr = (wid >> 1) * 64;
    const int wc = (wid & 1) * 64;
    const int l15 = lane & 15;
    const int lk8 = (lane >> 4) * 8;
    const int bm = blockIdx.y * 128;
    const int bn = blockIdx.x * 128;
    const int tn = tid & 127;
    const int tkh = (tid >> 7) * 16;

    const float* a_src[4];
    int a_soff[4];
#pragma unroll
    for (int p = 0; p < 4; ++p) {
        int idx = p * 256 + tid;
        int m = idx >> 3;
        int kf = (idx & 7) << 2;
        a_src[p] = A + (size_t)(bm + m) * K + kf;
        a_soff[p] = m * LDT + kf;
    }
    const int b_k = tid >> 5;
    const int b_n = (tid & 31) * 4;
    const bool bok = (bn + b_n + 3 < N);
    const float* b_src[4];
#pragma unroll
    for (int p = 0; p < 4; ++p)
        b_src[p] = B + (size_t)(p * 8 + b_k) * N + bn + b_n;
    int aoff[4], boff[4];
#pragma unroll
    for (int mi = 0; mi < 4; ++mi) aoff[mi] = (wr + mi * 16 + l15) * LDT + lk8;
#pragma unroll
    for (int ni = 0; ni < 4; ++ni) boff[ni] = (wc + ni * 16 + l15) * LDT + lk8;

    f32x4 accM[4][4];
    f32x4 accR[4][4];
#pragma unroll
    for (int i = 0; i < 4; ++i)
#pragma unroll
        for (int j = 0; j < 4; ++j) {
            accM[i][j] = (f32x4){0.f, 0.f, 0.f, 0.f};
            accR[i][j] = (f32x4){0.f, 0.f, 0.f, 0.f};
        }

    float4 avr[4], bvr[4];
#pragma unroll
    for (int p = 0; p < 4; ++p) avr[p] = *(const float4*)(a_src[p]);
#pragma unroll
    for (int p = 0; p < 4; ++p)
        bvr[p] = bok ? *(const float4*)(b_src[p]) : make_float4(0.f, 0.f, 0.f, 0.f);

    for (int k0 = 0; k0 < K; k0 += 32) {
        __syncthreads();
#pragma unroll
        for (int p = 0; p < 4; ++p) {
            unsigned w0a, w1a, w0b, w1b;
            tsplit2_pair(avr[p].x, avr[p].y, w0a, w1a);
            tsplit2_pair(avr[p].z, avr[p].w, w0b, w1b);
            *(uint2*)&as[a_soff[p]]      = make_uint2(w0a, w0b);
            *(uint2*)&as[PT + a_soff[p]] = make_uint2(w1a, w1b);
        }
#pragma unroll
        for (int p = 0; p < 4; ++p)
            *(float4*)&bsrc[(p * 8 + b_k) * 128 + b_n] = bvr[p];

        int kn = k0 + 32;
        if (kn < K) {
#pragma unroll
            for (int p = 0; p < 4; ++p) avr[p] = *(const float4*)(a_src[p] + kn);
#pragma unroll
            for (int p = 0; p < 4; ++p)
                bvr[p] = bok ? *(const float4*)(b_src[p] + (size_t)kn * N)
                             : make_float4(0.f, 0.f, 0.f, 0.f);
        }
        __syncthreads();

#pragma unroll
        for (int q = 0; q < 4; ++q) {
            int kq = tkh + q * 4;
            float f0 = bsrc[(kq + 0) * 128 + tn];
            float f1 = bsrc[(kq + 1) * 128 + tn];
            float f2 = bsrc[(kq + 2) * 128 + tn];
            float f3 = bsrc[(kq + 3) * 128 + tn];
            unsigned w0a, w1a, w0b, w1b;
            tsplit2_pair(f0, f1, w0a, w1a);
            tsplit2_pair(f2, f3, w0b, w1b);
            int off = tn * LDT + kq;
            *(uint2*)&bs[off]      = make_uint2(w0a, w0b);
            *(uint2*)&bs[PT + off] = make_uint2(w1a, w1b);
        }
        __syncthreads();

        bf16x8 af[2][4];
#pragma unroll
        for (int p = 0; p < 2; ++p)
#pragma unroll
            for (int mi = 0; mi < 4; ++mi)
                af[p][mi] = *(const bf16x8*)&as[p * PT + aoff[mi]];

#pragma unroll
        for (int q = 0; q < 2; ++q) {
            bf16x8 bf[4];
#pragma unroll
            for (int ni = 0; ni < 4; ++ni)
                bf[ni] = *(const bf16x8*)&bs[q * PT + boff[ni]];
#pragma unroll
            for (int p = 0; p < 2; ++p) {
                if (p + q > 1) continue;
                if (p == 0 && q == 0) {
#pragma unroll
                    for (int mi = 0; mi < 4; ++mi)
#pragma unroll
                        for (int ni = 0; ni < 4; ++ni)
                            accM[mi][ni] = __builtin_amdgcn_mfma_f32_16x16x32_bf16(
                                af[0][mi], bf[ni], accM[mi][ni], 0, 0, 0);
                } else {
#pragma unroll
                    for (int mi = 0; mi < 4; ++mi)
#pragma unroll
                        for (int ni = 0; ni < 4; ++ni)
                            accR[mi][ni] = __builtin_amdgcn_mfma_f32_16x16x32_bf16(
                                af[p][mi], bf[ni], accR[mi][ni], 0, 0, 0);
                }
            }
        }
    }

    const int rsub = (lane >> 4) * 4;
#pragma unroll
    for (int mi = 0; mi < 4; ++mi) {
        int row0 = bm + wr + mi * 16 + rsub;
#pragma unroll
        for (int ni = 0; ni < 4; ++ni) {
            int col = bn + wc + ni * 16 + l15;
            if (col < N) {
                float bb = bias[col];
#pragma unroll
                for (int r = 0; r < 4; ++r) {
                    float s = accR[mi][ni][r] + accM[mi][ni][r];
                    C[(size_t)(row0 + r) * N + col] = fmaxf(s + bb, 0.f);
                }
            }
        }
    }
}

// ---- k-winner (exact top-512, radix on fp32 bits, jax leftmost ties) -------
__global__ __launch_bounds__(256)
void kwinner_stripes(float* h2, const float* bscores)
{
    const int row = blockIdx.x;
    const int tid = threadIdx.x;
    float* rowp = h2 + (size_t)row * DDIM;

    __shared__ float  mv[DDIM];
    __shared__ int    ired[256];
    __shared__ double dred[256];
    __shared__ int    warr[4];
    __shared__ double ssum[128];
    __shared__ float  smk[128];

#pragma unroll
    for (int i = 0; i < 32; ++i) {
        int j = tid + i * 256;
        mv[j] = expf(0.0f - bscores[j]) * rowp[j];   // BETA=1, GAMMA=0
    }
    __syncthreads();

    unsigned t = 0;
    for (int bit = 30; bit >= 0; --bit) {
        unsigned cand = t | (1u << bit);
        int cnt = 0;
#pragma unroll
        for (int i = 0; i < 32; ++i)
            cnt += (__float_as_uint(mv[tid + i * 256]) >= cand) ? 1 : 0;
        for (int off = 32; off; off >>= 1) cnt += __shfl_down(cnt, off);
        if ((tid & 63) == 0) warr[tid >> 6] = cnt;
        __syncthreads();
        int tot = warr[0] + warr[1] + warr[2] + warr[3];
        __syncthreads();
        if (tot >= KNEUR) t = cand;
    }
    {
        int cnt = 0;
#pragma unroll
        for (int i = 0; i < 32; ++i)
            cnt += (__float_as_uint(mv[tid + i * 256]) > t) ? 1 : 0;
        for (int off = 32; off; off >>= 1) cnt += __shfl_down(cnt, off);
        if ((tid & 63) == 0) warr[tid >> 6] = cnt;
        __syncthreads();
    }
    const int need_eq = KNEUR - (warr[0] + warr[1] + warr[2] + warr[3]);
    __syncthreads();

    const int base = tid * 32;
    int myeq = 0;
#pragma unroll
    for (int i = 0; i < 32; ++i)
        myeq += (__float_as_uint(mv[base + i]) == t) ? 1 : 0;
    int val = myeq;
    ired[tid] = val;
    __syncthreads();
    for (int s = 1; s < 256; s <<= 1) {
        int add = (tid >= s) ? ired[tid - s] : 0;
        __syncthreads();
        val += add;
        ired[tid] = val;
        __syncthreads();
    }
    const int before = val - myeq;

    double partial = 0.0;
    int eqseen = 0;
#pragma unroll
    for (int i = 0; i < 32; ++i) {
        int j = base + i;
        float m = mv[j];
        unsigned u = __float_as_uint(m);
        bool sel = (u > t) || (u == t && (before + eqseen) < need_eq);
        if (u == t) ++eqseen;
        float code = sel ? m * rowp[j] : 0.f;
        mv[j] = code;
        partial += (double)code;
    }
    dred[tid] = partial;
    __syncthreads();
    if (tid < 128) ssum[tid] = dred[2 * tid] + dred[2 * tid + 1];
    __syncthreads();

    if (tid < 128) {
        double v = ssum[tid];
        int rank = 0;
        for (int j = 0; j < 128; ++j) {
            double w = ssum[j];
            rank += (w > v) ? 1 : 0;
            rank += (w == v && j < tid) ? 1 : 0;
        }
        smk[tid] = (rank < KSTR) ? 1.f : 0.f;
    }
    __syncthreads();

#pragma unroll
    for (int i = 0; i < 32; ++i) {
        int j = tid + i * 256;
        rowp[j] = mv[j] * smk[j >> 6];
    }
}

// ---------------------------------------------------------------------------
extern "C" void kernel_launch(void* const* d_in, const int* in_sizes, int n_in,
                              void* d_out, int out_size, void* d_ws, size_t ws_size,
                              hipStream_t stream)
{
    float* out = (float*)d_out;
    const unsigned long long on = (unsigned long long)out_size;

    if (n_in != 10) {
        Net_49976239456390_kernel<<<1024, 256, 0, stream>>>(out, on, 55.f);
        return;
    }
    if (in_sizes[0] != BDIM * XDIM || in_sizes[3] != IDIM * DDIM || in_sizes[9] != DDIM) {
        Net_49976239456390_kernel<<<1024, 256, 0, stream>>>(out, on, 66.f);
        return;
    }
    const size_t need = (size_t)BDIM * IDIM * 4 + (size_t)BDIM * DDIM * 4;
    if (need > ws_size) {
        Net_49976239456390_kernel<<<1024, 256, 0, stream>>>(out, on, 99.f);
        return;
    }

    Net_49976239456390_kernel<<<1024, 256, 0, stream>>>(out, on, 7.f);

    const float* x   = (const float*)d_in[0];
    const float* W1  = (const float*)d_in[1];
    const float* b1  = (const float*)d_in[2];
    const float* W2  = (const float*)d_in[3];
    const float* b2  = (const float*)d_in[4];
    const float* W3  = (const float*)d_in[5];
    const float* b3  = (const float*)d_in[6];
    const float* W4  = (const float*)d_in[7];
    const float* b4  = (const float*)d_in[8];
    const float* bsc = (const float*)d_in[9];

    float* h1 = (float*)d_ws;                     // [B][I], reused as h3
    float* h2 = h1 + (size_t)BDIM * IDIM;         // [B][D], flat in place

    dim3 blk(256);
    gemm_relu<<<dim3(IDIM / 128, BDIM / 128), blk, 0, stream>>>(
        x, W1, b1, h1, IDIM, XDIM);
    gemm2_split<<<dim3(DDIM / 128, BDIM / 128), blk, 0, stream>>>(
        h1, W2, b2, h2);
    kwinner_stripes<<<dim3(BDIM), blk, 0, stream>>>(h2, bsc);
    gemm_v2split<<<dim3(IDIM / 128, BDIM / 128), blk, 0, stream>>>(
        h2, W3, b3, h1, IDIM, DDIM);
    gemm_v2split<<<dim3((XDIM + 127) / 128, BDIM / 128), blk, 0, stream>>>(
        h1, W4, b4, out, XDIM, IDIM);
}

// Round 13
// 6039.750 us; speedup vs baseline: 1.5245x; 1.0111x over previous
//
#include <hip/hip_runtime.h>
#include <hip/hip_bf16.h>

// ---------------------------------------------------------------------------
// Net_49976239456390 — Round 13: gemm2 B-path de-round-trip (single change).
//   gemm2_split: B tile read DIRECTLY from global in transposed coalesced
//   pattern (lane=column, loop k) -> split3 -> bs planes. Eliminates the
//   bsrc LDS round-trip (4 b128 writes + 16 b32 reads per thread-iter),
//   one barrier (3->2), and 16 KB LDS. Loads issue before the first
//   barrier, consumed right after (dead before MFMA -> no r11-style spill).
//   MFMA operands bit-identical to r12 -> absmax must stay 6.103516e-05.
// gemm1, kwinner, gemm_v2split, launcher: byte-identical to round 12.
// ---------------------------------------------------------------------------

#define BDIM 8192
#define IDIM 4096
#define DDIM 8192
#define XDIM 784
#define KNEUR 512
#define KSTR  16

typedef __attribute__((ext_vector_type(8))) short bf16x8;
typedef __attribute__((ext_vector_type(4))) float f32x4;

#define LDT 40            // padded LDS row: 40 shorts = 80 B
#define PT  (128 * LDT)   // one plane tile in shorts

// identifier-named kernel: grid-stride fp32 fill (sentinel / error codes)
__global__ void Net_49976239456390_kernel(float* out, unsigned long long n, float v)
{
    unsigned long long i = (unsigned long long)blockIdx.x * blockDim.x + threadIdx.x;
    unsigned long long step = (unsigned long long)gridDim.x * blockDim.x;
    for (; i < n; i += step) out[i] = v;
}

// ---- RNE 3-term split (round-7 gemm2 path) ----------------------------------
__device__ __forceinline__ void split3(float f, short& s0, short& s1, short& s2)
{
    __hip_bfloat16 b0 = __float2bfloat16(f);
    float r1 = f - __bfloat162float(b0);
    __hip_bfloat16 b1 = __float2bfloat16(r1);
    float r2 = r1 - __bfloat162float(b1);
    __hip_bfloat16 b2 = __float2bfloat16(r2);
    s0 = *(short*)&b0; s1 = *(short*)&b1; s2 = *(short*)&b2;
}

// ---- truncation 2-term split, packed pair (round-11 v2split path) ----------
__device__ __forceinline__ void tsplit2_pair(float f0, float f1,
                                             unsigned& w0, unsigned& w1)
{
    unsigned u0 = __float_as_uint(f0), u1 = __float_as_uint(f1);
    unsigned h0 = u0 & 0xFFFF0000u,  h1 = u1 & 0xFFFF0000u;
    float r0 = f0 - __uint_as_float(h0);
    float r1 = f1 - __uint_as_float(h1);
    w0 = (h0 >> 16) | h1;
    w1 = (__float_as_uint(r0) >> 16) | (__float_as_uint(r1) & 0xFFFF0000u);
}

// ---- fp32 GEMM: C = relu(A @ B + bias) (GEMM1) ------------------------------
__global__ __launch_bounds__(256)
void gemm_relu(const float* A, const float* B, const float* bias, float* C,
               int N, int K)
{
    __shared__ float as[8][128];
    __shared__ float bs[8][128];

    const int tid = threadIdx.x;
    const int bm = blockIdx.y * 128;
    const int bn = blockIdx.x * 128;
    const int tx = tid & 15, ty = tid >> 4;
    const int r0 = ty * 4, c0 = tx * 4;
    const int a_m = tid >> 1, a_k = (tid & 1) * 4;
    const int b_k = tid >> 5, b_n = (tid & 31) * 4;

    const float* Ap = A + (size_t)(bm + a_m) * K + a_k;
    const float* Bp = B + (size_t)b_k * N + (bn + b_n);
    const bool bok = (bn + b_n + 3 < N);

    float acc[8][8];
#pragma unroll
    for (int i = 0; i < 8; ++i)
#pragma unroll
        for (int j = 0; j < 8; ++j) acc[i][j] = 0.f;

    for (int k0 = 0; k0 < K; k0 += 8) {
        float4 av = *(const float4*)(Ap + k0);
        float4 bv = make_float4(0.f, 0.f, 0.f, 0.f);
        if (bok) bv = *(const float4*)(Bp + (size_t)k0 * N);
        __syncthreads();
        as[a_k + 0][a_m] = av.x;
        as[a_k + 1][a_m] = av.y;
        as[a_k + 2][a_m] = av.z;
        as[a_k + 3][a_m] = av.w;
        *(float4*)&bs[b_k][b_n] = bv;
        __syncthreads();
#pragma unroll
        for (int k = 0; k < 8; ++k) {
            float4 a0 = *(const float4*)&as[k][r0];
            float4 a1 = *(const float4*)&as[k][r0 + 64];
            float4 b0 = *(const float4*)&bs[k][c0];
            float4 b1 = *(const float4*)&bs[k][c0 + 64];
            float aa[8] = {a0.x, a0.y, a0.z, a0.w, a1.x, a1.y, a1.z, a1.w};
            float bb[8] = {b0.x, b0.y, b0.z, b0.w, b1.x, b1.y, b1.z, b1.w};
#pragma unroll
            for (int i = 0; i < 8; ++i)
#pragma unroll
                for (int j = 0; j < 8; ++j)
                    acc[i][j] = fmaf(aa[i], bb[j], acc[i][j]);
        }
    }

#pragma unroll
    for (int i = 0; i < 8; ++i) {
        const int rr = bm + r0 + ((i >> 2) << 6) + (i & 3);
        float* op = C + (size_t)rr * N;
#pragma unroll
        for (int j = 0; j < 8; ++j) {
            int cc = bn + c0 + ((j >> 2) << 6) + (j & 3);
            if (cc < N)
                op[cc] = fmaxf(acc[i][j] + bias[cc], 0.f);
        }
    }
}

// ---- GEMM2: h2 = relu(h1 @ W2 + b2), 3-term split, 6 products ---------------
// r12 structure with the bsrc round-trip removed: B read transposed from
// global (coalesced: lane = column), split in regs, written to bs planes.
__global__ __launch_bounds__(256, 2)
void gemm2_split(const float* __restrict__ A, const float* __restrict__ B,
                 const float* __restrict__ bias, float* __restrict__ C)
{
    __shared__ short as[3][128 * LDT];   // 30720 B
    __shared__ short bs[3][128 * LDT];   // 30720 B

    const int tid = threadIdx.x;
    const int lane = tid & 63;
    const int wid = tid >> 6;
    const int wr = (wid >> 1) * 64;
    const int wc = (wid & 1) * 64;
    const int l15 = lane & 15;
    const int lk8 = (lane >> 4) * 8;
    const int bm = blockIdx.y * 128;
    const int bn = blockIdx.x * 128;

    const int tn = tid & 127;            // column within tile
    const int tkh = (tid >> 7) * 16;     // k-half (0 or 16)

    // loop-invariant source pointers
    const float* a_src[4];
    int a_soff[4];
#pragma unroll
    for (int p = 0; p < 4; ++p) {
        int idx = p * 256 + tid;
        int m = idx >> 3;
        int kf = (idx & 7) << 2;
        a_src[p] = A + (size_t)(bm + m) * IDIM + kf;
        a_soff[p] = m * LDT + kf;
    }
    const float* b_col = B + (size_t)tkh * DDIM + bn + tn;   // + k*DDIM walks k

    f32x4 accM[4][4];
    f32x4 accR[4][4];
#pragma unroll
    for (int i = 0; i < 4; ++i)
#pragma unroll
        for (int j = 0; j < 4; ++j) {
            accM[i][j] = (f32x4){0.f, 0.f, 0.f, 0.f};
            accR[i][j] = (f32x4){0.f, 0.f, 0.f, 0.f};
        }

    for (int k0 = 0; k0 < IDIM; k0 += 32) {
        // issue loads before the barrier (no LDS dependency; consumed after)
        float4 av[4];
#pragma unroll
        for (int p = 0; p < 4; ++p)
            av[p] = *(const float4*)(a_src[p] + k0);
        float bcol[16];
#pragma unroll
        for (int e = 0; e < 16; ++e)
            bcol[e] = b_col[(size_t)(k0 + e) * DDIM];

        __syncthreads();   // prior iteration's frag reads done

        // stage A: split -> as planes
#pragma unroll
        for (int p = 0; p < 4; ++p) {
            short s0[4], s1[4], s2[4];
            split3(av[p].x, s0[0], s1[0], s2[0]);
            split3(av[p].y, s0[1], s1[1], s2[1]);
            split3(av[p].z, s0[2], s1[2], s2[2]);
            split3(av[p].w, s0[3], s1[3], s2[3]);
            int off = a_soff[p];
            *(short4*)&as[0][off] = make_short4(s0[0], s0[1], s0[2], s0[3]);
            *(short4*)&as[1][off] = make_short4(s1[0], s1[1], s1[2], s1[3]);
            *(short4*)&as[2][off] = make_short4(s2[0], s2[1], s2[2], s2[3]);
        }
        // stage B: split transposed column segments -> bs planes
#pragma unroll
        for (int q = 0; q < 4; ++q) {
            short s0[4], s1[4], s2[4];
#pragma unroll
            for (int e = 0; e < 4; ++e)
                split3(bcol[q * 4 + e], s0[e], s1[e], s2[e]);
            int off = tn * LDT + tkh + q * 4;
            *(short4*)&bs[0][off] = make_short4(s0[0], s0[1], s0[2], s0[3]);
            *(short4*)&bs[1][off] = make_short4(s1[0], s1[1], s1[2], s1[3]);
            *(short4*)&bs[2][off] = make_short4(s2[0], s2[1], s2[2], s2[3]);
        }
        __syncthreads();   // tiles ready

        bf16x8 af[3][4];
#pragma unroll
        for (int p = 0; p < 3; ++p)
#pragma unroll
            for (int mi = 0; mi < 4; ++mi)
                af[p][mi] = *(const bf16x8*)&as[p][(wr + mi * 16 + l15) * LDT + lk8];

#pragma unroll
        for (int q = 0; q < 3; ++q) {
            bf16x8 bf[4];
#pragma unroll
            for (int ni = 0; ni < 4; ++ni)
                bf[ni] = *(const bf16x8*)&bs[q][(wc + ni * 16 + l15) * LDT + lk8];
#pragma unroll
            for (int p = 0; p < 3; ++p) {
                if (p + q > 2) continue;
                if (p == 0 && q == 0) {
#pragma unroll
                    for (int mi = 0; mi < 4; ++mi)
#pragma unroll
                        for (int ni = 0; ni < 4; ++ni)
                            accM[mi][ni] = __builtin_amdgcn_mfma_f32_16x16x32_bf16(
                                af[0][mi], bf[ni], accM[mi][ni], 0, 0, 0);
                } else {
#pragma unroll
                    for (int mi = 0; mi < 4; ++mi)
#pragma unroll
                        for (int ni = 0; ni < 4; ++ni)
                            accR[mi][ni] = __builtin_amdgcn_mfma_f32_16x16x32_bf16(
                                af[p][mi], bf[ni], accR[mi][ni], 0, 0, 0);
                }
            }
        }
    }

    const int rsub = (lane >> 4) * 4;
#pragma unroll
    for (int mi = 0; mi < 4; ++mi) {
        int row0 = bm + wr + mi * 16 + rsub;
#pragma unroll
        for (int ni = 0; ni < 4; ++ni) {
            int col = bn + wc + ni * 16 + l15;
            float bb = bias[col];
#pragma unroll
            for (int r = 0; r < 4; ++r) {
                float s = accR[mi][ni][r] + accM[mi][ni][r];
                C[(size_t)(row0 + r) * DDIM + col] = fmaxf(s + bb, 0.f);
            }
        }
    }
}

// ---- value-only split GEMM: 2-term, 3 products (GEMM3 and GEMM4) ------------
// EXACT round-11/12 code.
__global__ __launch_bounds__(256, 2)
void gemm_v2split(const float* __restrict__ A, const float* __restrict__ B,
                  const float* __restrict__ bias, float* __restrict__ C,
                  int N, int K)
{
    __shared__ short as[2 * PT];
    __shared__ short bs[2 * PT];
    __shared__ float bsrc[32 * 128];

    const int tid = threadIdx.x;
    const int lane = tid & 63;
    const int wid = tid >> 6;
    const int wr = (wid >> 1) * 64;
    const int wc = (wid & 1) * 64;
    const int l15 = lane & 15;
    const int lk8 = (lane >> 4) * 8;
    const int bm = blockIdx.y * 128;
    const int bn = blockIdx.x * 128;
    const int tn = tid & 127;
    const int tkh = (tid >> 7) * 16;

    const float* a_src[4];
    int a_soff[4];
#pragma unroll
    for (int p = 0; p < 4; ++p) {
        int idx = p * 256 + tid;
        int m = idx >> 3;
        int kf = (idx & 7) << 2;
        a_src[p] = A + (size_t)(bm + m) * K + kf;
        a_soff[p] = m * LDT + kf;
    }
    const int b_k = tid >> 5;
    const int b_n = (tid & 31) * 4;
    const bool bok = (bn + b_n + 3 < N);
    const float* b_src[4];
#pragma unroll
    for (int p = 0; p < 4; ++p)
        b_src[p] = B + (size_t)(p * 8 + b_k) * N + bn + b_n;
    int aoff[4], boff[4];
#pragma unroll
    for (int mi = 0; mi < 4; ++mi) aoff[mi] = (wr + mi * 16 + l15) * LDT + lk8;
#pragma unroll
    for (int ni = 0; ni < 4; ++ni) boff[ni] = (wc + ni * 16 + l15) * LDT + lk8;

    f32x4 accM[4][4];
    f32x4 accR[4][4];
#pragma unroll
    for (int i = 0; i < 4; ++i)
#pragma unroll
        for (int j = 0; j < 4; ++j) {
            accM[i][j] = (f32x4){0.f, 0.f, 0.f, 0.f};
            accR[i][j] = (f32x4){0.f, 0.f, 0.f, 0.f};
        }

    float4 avr[4], bvr[4];
#pragma unroll
    for (int p = 0; p < 4; ++p) avr[p] = *(const float4*)(a_src[p]);
#pragma unroll
    for (int p = 0; p < 4; ++p)
        bvr[p] = bok ? *(const float4*)(b_src[p]) : make_float4(0.f, 0.f, 0.f, 0.f);

    for (int k0 = 0; k0 < K; k0 += 32) {
        __syncthreads();
#pragma unroll
        for (int p = 0; p < 4; ++p) {
            unsigned w0a, w1a, w0b, w1b;
            tsplit2_pair(avr[p].x, avr[p].y, w0a, w1a);
            tsplit2_pair(avr[p].z, avr[p].w, w0b, w1b);
            *(uint2*)&as[a_soff[p]]      = make_uint2(w0a, w0b);
            *(uint2*)&as[PT + a_soff[p]] = make_uint2(w1a, w1b);
        }
#pragma unroll
        for (int p = 0; p < 4; ++p)
            *(float4*)&bsrc[(p * 8 + b_k) * 128 + b_n] = bvr[p];

        int kn = k0 + 32;
        if (kn < K) {
#pragma unroll
            for (int p = 0; p < 4; ++p) avr[p] = *(const float4*)(a_src[p] + kn);
#pragma unroll
            for (int p = 0; p < 4; ++p)
                bvr[p] = bok ? *(const float4*)(b_src[p] + (size_t)kn * N)
                             : make_float4(0.f, 0.f, 0.f, 0.f);
        }
        __syncthreads();

#pragma unroll
        for (int q = 0; q < 4; ++q) {
            int kq = tkh + q * 4;
            float f0 = bsrc[(kq + 0) * 128 + tn];
            float f1 = bsrc[(kq + 1) * 128 + tn];
            float f2 = bsrc[(kq + 2) * 128 + tn];
            float f3 = bsrc[(kq + 3) * 128 + tn];
            unsigned w0a, w1a, w0b, w1b;
            tsplit2_pair(f0, f1, w0a, w1a);
            tsplit2_pair(f2, f3, w0b, w1b);
            int off = tn * LDT + kq;
            *(uint2*)&bs[off]      = make_uint2(w0a, w0b);
            *(uint2*)&bs[PT + off] = make_uint2(w1a, w1b);
        }
        __syncthreads();

        bf16x8 af[2][4];
#pragma unroll
        for (int p = 0; p < 2; ++p)
#pragma unroll
            for (int mi = 0; mi < 4; ++mi)
                af[p][mi] = *(const bf16x8*)&as[p * PT + aoff[mi]];

#pragma unroll
        for (int q = 0; q < 2; ++q) {
            bf16x8 bf[4];
#pragma unroll
            for (int ni = 0; ni < 4; ++ni)
                bf[ni] = *(const bf16x8*)&bs[q * PT + boff[ni]];
#pragma unroll
            for (int p = 0; p < 2; ++p) {
                if (p + q > 1) continue;
                if (p == 0 && q == 0) {
#pragma unroll
                    for (int mi = 0; mi < 4; ++mi)
#pragma unroll
                        for (int ni = 0; ni < 4; ++ni)
                            accM[mi][ni] = __builtin_amdgcn_mfma_f32_16x16x32_bf16(
                                af[0][mi], bf[ni], accM[mi][ni], 0, 0, 0);
                } else {
#pragma unroll
                    for (int mi = 0; mi < 4; ++mi)
#pragma unroll
                        for (int ni = 0; ni < 4; ++ni)
                            accR[mi][ni] = __builtin_amdgcn_mfma_f32_16x16x32_bf16(
                                af[p][mi], bf[ni], accR[mi][ni], 0, 0, 0);
                }
            }
        }
    }

    const int rsub = (lane >> 4) * 4;
#pragma unroll
    for (int mi = 0; mi < 4; ++mi) {
        int row0 = bm + wr + mi * 16 + rsub;
#pragma unroll
        for (int ni = 0; ni < 4; ++ni) {
            int col = bn + wc + ni * 16 + l15;
            if (col < N) {
                float bb = bias[col];
#pragma unroll
                for (int r = 0; r < 4; ++r) {
                    float s = accR[mi][ni][r] + accM[mi][ni][r];
                    C[(size_t)(row0 + r) * N + col] = fmaxf(s + bb, 0.f);
                }
            }
        }
    }
}

// ---- k-winner (exact top-512, radix on fp32 bits, jax leftmost ties) -------
__global__ __launch_bounds__(256)
void kwinner_stripes(float* h2, const float* bscores)
{
    const int row = blockIdx.x;
    const int tid = threadIdx.x;
    float* rowp = h2 + (size_t)row * DDIM;

    __shared__ float  mv[DDIM];
    __shared__ int    ired[256];
    __shared__ double dred[256];
    __shared__ int    warr[4];
    __shared__ double ssum[128];
    __shared__ float  smk[128];

#pragma unroll
    for (int i = 0; i < 32; ++i) {
        int j = tid + i * 256;
        mv[j] = expf(0.0f - bscores[j]) * rowp[j];   // BETA=1, GAMMA=0
    }
    __syncthreads();

    unsigned t = 0;
    for (int bit = 30; bit >= 0; --bit) {
        unsigned cand = t | (1u << bit);
        int cnt = 0;
#pragma unroll
        for (int i = 0; i < 32; ++i)
            cnt += (__float_as_uint(mv[tid + i * 256]) >= cand) ? 1 : 0;
        for (int off = 32; off; off >>= 1) cnt += __shfl_down(cnt, off);
        if ((tid & 63) == 0) warr[tid >> 6] = cnt;
        __syncthreads();
        int tot = warr[0] + warr[1] + warr[2] + warr[3];
        __syncthreads();
        if (tot >= KNEUR) t = cand;
    }
    {
        int cnt = 0;
#pragma unroll
        for (int i = 0; i < 32; ++i)
            cnt += (__float_as_uint(mv[tid + i * 256]) > t) ? 1 : 0;
        for (int off = 32; off; off >>= 1) cnt += __shfl_down(cnt, off);
        if ((tid & 63) == 0) warr[tid >> 6] = cnt;
        __syncthreads();
    }
    const int need_eq = KNEUR - (warr[0] + warr[1] + warr[2] + warr[3]);
    __syncthreads();

    const int base = tid * 32;
    int myeq = 0;
#pragma unroll
    for (int i = 0; i < 32; ++i)
        myeq += (__float_as_uint(mv[base + i]) == t) ? 1 : 0;
    int val = myeq;
    ired[tid] = val;
    __syncthreads();
    for (int s = 1; s < 256; s <<= 1) {
        int add = (tid >= s) ? ired[tid - s] : 0;
        __syncthreads();
        val += add;
        ired[tid] = val;
        __syncthreads();
    }
    const int before = val - myeq;

    double partial = 0.0;
    int eqseen = 0;
#pragma unroll
    for (int i = 0; i < 32; ++i) {
        int j = base + i;
        float m = mv[j];
        unsigned u = __float_as_uint(m);
        bool sel = (u > t) || (u == t && (before + eqseen) < need_eq);
        if (u == t) ++eqseen;
        float code = sel ? m * rowp[j] : 0.f;
        mv[j] = code;
        partial += (double)code;
    }
    dred[tid] = partial;
    __syncthreads();
    if (tid < 128) ssum[tid] = dred[2 * tid] + dred[2 * tid + 1];
    __syncthreads();

    if (tid < 128) {
        double v = ssum[tid];
        int rank = 0;
        for (int j = 0; j < 128; ++j) {
            double w = ssum[j];
            rank += (w > v) ? 1 : 0;
            rank += (w == v && j < tid) ? 1 : 0;
        }
        smk[tid] = (rank < KSTR) ? 1.f : 0.f;
    }
    __syncthreads();

#pragma unroll
    for (int i = 0; i < 32; ++i) {
        int j = tid + i * 256;
        rowp[j] = mv[j] * smk[j >> 6];
    }
}

// ---------------------------------------------------------------------------
extern "C" void kernel_launch(void* const* d_in, const int* in_sizes, int n_in,
                              void* d_out, int out_size, void* d_ws, size_t ws_size,
                              hipStream_t stream)
{
    float* out = (float*)d_out;
    const unsigned long long on = (unsigned long long)out_size;

    if (n_in != 10) {
        Net_49976239456390_kernel<<<1024, 256, 0, stream>>>(out, on, 55.f);
        return;
    }
    if (in_sizes[0] != BDIM * XDIM || in_sizes[3] != IDIM * DDIM || in_sizes[9] != DDIM) {
        Net_49976239456390_kernel<<<1024, 256, 0, stream>>>(out, on, 66.f);
        return;
    }
    const size_t need = (size_t)BDIM * IDIM * 4 + (size_t)BDIM * DDIM * 4;
    if (need > ws_size) {
        Net_49976239456390_kernel<<<1024, 256, 0, stream>>>(out, on, 99.f);
        return;
    }

    Net_49976239456390_kernel<<<1024, 256, 0, stream>>>(out, on, 7.f);

    const float* x   = (const float*)d_in[0];
    const float* W1  = (const float*)d_in[1];
    const float* b1  = (const float*)d_in[2];
    const float* W2  = (const float*)d_in[3];
    const float* b2  = (const float*)d_in[4];
    const float* W3  = (const float*)d_in[5];
    const float* b3  = (const float*)d_in[6];
    const float* W4  = (const float*)d_in[7];
    const float* b4  = (const float*)d_in[8];
    const float* bsc = (const float*)d_in[9];

    float* h1 = (float*)d_ws;                     // [B][I], reused as h3
    float* h2 = h1 + (size_t)BDIM * IDIM;         // [B][D], flat in place

    dim3 blk(256);
    gemm_relu<<<dim3(IDIM / 128, BDIM / 128), blk, 0, stream>>>(
        x, W1, b1, h1, IDIM, XDIM);
    gemm2_split<<<dim3(DDIM / 128, BDIM / 128), blk, 0, stream>>>(
        h1, W2, b2, h2);
    kwinner_stripes<<<dim3(BDIM), blk, 0, stream>>>(h2, bsc);
    gemm_v2split<<<dim3(IDIM / 128, BDIM / 128), blk, 0, stream>>>(
        h2, W3, b3, h1, IDIM, DDIM);
    gemm_v2split<<<dim3((XDIM + 127) / 128, BDIM / 128), blk, 0, stream>>>(
        h1, W4, b4, out, XDIM, IDIM);
}

// Round 14
// 5817.524 us; speedup vs baseline: 1.5827x; 1.0382x over previous
//
#include <hip/hip_runtime.h>
#include <hip/hip_bf16.h>

// ---------------------------------------------------------------------------
// Net_49976239456390 — Round 14: split-arithmetic cost reduction.
//   1. gemm2: RNE split3 -> truncation tsplit3_pair (exact decomposition,
//      ~half the VALU). Access structure byte-identical to r13 (the clean
//      single-variable test r10/r11 never ran).
//   2. gemm1: fp32 vector GEMM (~95 TF) -> same 3-term split-MFMA kernel,
//      unified template<KGUARD> with address-clamped K=784 tail guards.
// kwinner, gemm_v2split (GEMM3/4), launcher: unchanged from r13.
// ---------------------------------------------------------------------------

#define BDIM 8192
#define IDIM 4096
#define DDIM 8192
#define XDIM 784
#define KNEUR 512
#define KSTR  16

typedef __attribute__((ext_vector_type(8))) short bf16x8;
typedef __attribute__((ext_vector_type(4))) float f32x4;

#define LDT 40            // padded LDS row: 40 shorts = 80 B
#define PT  (128 * LDT)   // one plane tile in shorts

// identifier-named kernel: grid-stride fp32 fill (sentinel / error codes)
__global__ void Net_49976239456390_kernel(float* out, unsigned long long n, float v)
{
    unsigned long long i = (unsigned long long)blockIdx.x * blockDim.x + threadIdx.x;
    unsigned long long step = (unsigned long long)gridDim.x * blockDim.x;
    for (; i < n; i += step) out[i] = v;
}

// ---- exact truncation splits (packed pairs, little-endian short order) ------
// f = b0 + b1 + b2 exactly (8+8+8 mantissa bits; residuals exactly
// representable, so truncation at each stage loses nothing).
__device__ __forceinline__ void tsplit3_pair(float f0, float f1,
                                             unsigned& w0, unsigned& w1, unsigned& w2)
{
    unsigned u0 = __float_as_uint(f0), u1 = __float_as_uint(f1);
    unsigned h0 = u0 & 0xFFFF0000u,  h1 = u1 & 0xFFFF0000u;
    float r0 = f0 - __uint_as_float(h0);
    float r1 = f1 - __uint_as_float(h1);
    unsigned v0 = __float_as_uint(r0) & 0xFFFF0000u;
    unsigned v1 = __float_as_uint(r1) & 0xFFFF0000u;
    float s0 = r0 - __uint_as_float(v0);
    float s1 = r1 - __uint_as_float(v1);
    w0 = (h0 >> 16) | h1;
    w1 = (v0 >> 16) | v1;
    w2 = (__float_as_uint(s0) >> 16) | (__float_as_uint(s1) & 0xFFFF0000u);
}

__device__ __forceinline__ void tsplit2_pair(float f0, float f1,
                                             unsigned& w0, unsigned& w1)
{
    unsigned u0 = __float_as_uint(f0), u1 = __float_as_uint(f1);
    unsigned h0 = u0 & 0xFFFF0000u,  h1 = u1 & 0xFFFF0000u;
    float r0 = f0 - __uint_as_float(h0);
    float r1 = f1 - __uint_as_float(h1);
    w0 = (h0 >> 16) | h1;
    w1 = (__float_as_uint(r0) >> 16) | (__float_as_uint(r1) & 0xFFFF0000u);
}

// ---- 3-term split MFMA GEMM: C = relu(A @ B + bias) -------------------------
// A:[M][K] fp32, B:[K][N] fp32, C:[M][N] fp32. 128x128 tile, BK=32,
// 256 thr (2x2 waves of 64x64), 6 products (i+j<=2), dual accumulators.
// B read transposed-coalesced from global (r13 path). KGUARD: K%32 != 0
// tail handled with address-clamped, zero-filled loads (gemm1, K=784).
template<bool KG>
__global__ __launch_bounds__(256, 2)
void gemm_m3split(const float* __restrict__ A, const float* __restrict__ B,
                  const float* __restrict__ bias, float* __restrict__ C,
                  int N, int K)
{
    __shared__ short as[3][128 * LDT];   // 30720 B
    __shared__ short bs[3][128 * LDT];   // 30720 B

    const int tid = threadIdx.x;
    const int lane = tid & 63;
    const int wid = tid >> 6;
    const int wr = (wid >> 1) * 64;
    const int wc = (wid & 1) * 64;
    const int l15 = lane & 15;
    const int lk8 = (lane >> 4) * 8;
    const int bm = blockIdx.y * 128;
    const int bn = blockIdx.x * 128;

    const int tn = tid & 127;            // column within tile
    const int tkh = (tid >> 7) * 16;     // k-half (0 or 16)

    // loop-invariant source pointers
    const float* a_src[4];
    int a_soff[4], a_kf[4];
#pragma unroll
    for (int p = 0; p < 4; ++p) {
        int idx = p * 256 + tid;
        int m = idx >> 3;
        int kf = (idx & 7) << 2;
        a_src[p] = A + (size_t)(bm + m) * K + kf;
        a_soff[p] = m * LDT + kf;
        a_kf[p] = kf;
    }
    const float* b_col = B + (size_t)tkh * N + bn + tn;   // + k*N walks k

    f32x4 accM[4][4];
    f32x4 accR[4][4];
#pragma unroll
    for (int i = 0; i < 4; ++i)
#pragma unroll
        for (int j = 0; j < 4; ++j) {
            accM[i][j] = (f32x4){0.f, 0.f, 0.f, 0.f};
            accR[i][j] = (f32x4){0.f, 0.f, 0.f, 0.f};
        }

    for (int k0 = 0; k0 < K; k0 += 32) {
        // issue loads before the barrier (consumed right after; dead by MFMA)
        float4 av[4];
#pragma unroll
        for (int p = 0; p < 4; ++p) {
            if (!KG) {
                av[p] = *(const float4*)(a_src[p] + k0);
            } else {
                int kb = k0 + a_kf[p];
                if (kb + 3 < K) {
                    av[p] = *(const float4*)(a_src[p] + k0);
                } else {
                    float t[4];
#pragma unroll
                    for (int e = 0; e < 4; ++e) {
                        float tv = a_src[p][(kb + e < K) ? (k0 + e) : 0];
                        t[e] = (kb + e < K) ? tv : 0.f;
                    }
                    av[p] = make_float4(t[0], t[1], t[2], t[3]);
                }
            }
        }
        float bcol[16];
#pragma unroll
        for (int e = 0; e < 16; ++e) {
            if (!KG) {
                bcol[e] = b_col[(size_t)(k0 + e) * N];
            } else {
                int kk = tkh + k0 + e;
                float tv = b_col[(kk < K) ? (size_t)(k0 + e) * N : 0];
                bcol[e] = (kk < K) ? tv : 0.f;
            }
        }

        __syncthreads();   // prior iteration's frag reads done

        // stage A: trunc split -> as planes
#pragma unroll
        for (int p = 0; p < 4; ++p) {
            unsigned w0a, w1a, w2a, w0b, w1b, w2b;
            tsplit3_pair(av[p].x, av[p].y, w0a, w1a, w2a);
            tsplit3_pair(av[p].z, av[p].w, w0b, w1b, w2b);
            int off = a_soff[p];
            *(uint2*)&as[0][off] = make_uint2(w0a, w0b);
            *(uint2*)&as[1][off] = make_uint2(w1a, w1b);
            *(uint2*)&as[2][off] = make_uint2(w2a, w2b);
        }
        // stage B: trunc split transposed column segments -> bs planes
#pragma unroll
        for (int q = 0; q < 4; ++q) {
            unsigned w0a, w1a, w2a, w0b, w1b, w2b;
            tsplit3_pair(bcol[q * 4 + 0], bcol[q * 4 + 1], w0a, w1a, w2a);
            tsplit3_pair(bcol[q * 4 + 2], bcol[q * 4 + 3], w0b, w1b, w2b);
            int off = tn * LDT + tkh + q * 4;
            *(uint2*)&bs[0][off] = make_uint2(w0a, w0b);
            *(uint2*)&bs[1][off] = make_uint2(w1a, w1b);
            *(uint2*)&bs[2][off] = make_uint2(w2a, w2b);
        }
        __syncthreads();   // tiles ready

        bf16x8 af[3][4];
#pragma unroll
        for (int p = 0; p < 3; ++p)
#pragma unroll
            for (int mi = 0; mi < 4; ++mi)
                af[p][mi] = *(const bf16x8*)&as[p][(wr + mi * 16 + l15) * LDT + lk8];

#pragma unroll
        for (int q = 0; q < 3; ++q) {
            bf16x8 bf[4];
#pragma unroll
            for (int ni = 0; ni < 4; ++ni)
                bf[ni] = *(const bf16x8*)&bs[q][(wc + ni * 16 + l15) * LDT + lk8];
#pragma unroll
            for (int p = 0; p < 3; ++p) {
                if (p + q > 2) continue;
                if (p == 0 && q == 0) {
#pragma unroll
                    for (int mi = 0; mi < 4; ++mi)
#pragma unroll
                        for (int ni = 0; ni < 4; ++ni)
                            accM[mi][ni] = __builtin_amdgcn_mfma_f32_16x16x32_bf16(
                                af[0][mi], bf[ni], accM[mi][ni], 0, 0, 0);
                } else {
#pragma unroll
                    for (int mi = 0; mi < 4; ++mi)
#pragma unroll
                        for (int ni = 0; ni < 4; ++ni)
                            accR[mi][ni] = __builtin_amdgcn_mfma_f32_16x16x32_bf16(
                                af[p][mi], bf[ni], accR[mi][ni], 0, 0, 0);
                }
            }
        }
    }

    const int rsub = (lane >> 4) * 4;
#pragma unroll
    for (int mi = 0; mi < 4; ++mi) {
        int row0 = bm + wr + mi * 16 + rsub;
#pragma unroll
        for (int ni = 0; ni < 4; ++ni) {
            int col = bn + wc + ni * 16 + l15;
            float bb = bias[col];
#pragma unroll
            for (int r = 0; r < 4; ++r) {
                float s = accR[mi][ni][r] + accM[mi][ni][r];
                C[(size_t)(row0 + r) * N + col] = fmaxf(s + bb, 0.f);
            }
        }
    }
}

// ---- value-only split GEMM: 2-term, 3 products (GEMM3 and GEMM4) ------------
// EXACT round-11/12/13 code.
__global__ __launch_bounds__(256, 2)
void gemm_v2split(const float* __restrict__ A, const float* __restrict__ B,
                  const float* __restrict__ bias, float* __restrict__ C,
                  int N, int K)
{
    __shared__ short as[2 * PT];
    __shared__ short bs[2 * PT];
    __shared__ float bsrc[32 * 128];

    const int tid = threadIdx.x;
    const int lane = tid & 63;
    const int wid = tid >> 6;
    const int wr = (wid >> 1) * 64;
    const int wc = (wid & 1) * 64;
    const int l15 = lane & 15;
    const int lk8 = (lane >> 4) * 8;
    const int bm = blockIdx.y * 128;
    const int bn = blockIdx.x * 128;
    const int tn = tid & 127;
    const int tkh = (tid >> 7) * 16;

    const float* a_src[4];
    int a_soff[4];
#pragma unroll
    for (int p = 0; p < 4; ++p) {
        int idx = p * 256 + tid;
        int m = idx >> 3;
        int kf = (idx & 7) << 2;
        a_src[p] = A + (size_t)(bm + m) * K + kf;
        a_soff[p] = m * LDT + kf;
    }
    const int b_k = tid >> 5;
    const int b_n = (tid & 31) * 4;
    const bool bok = (bn + b_n + 3 < N);
    const float* b_src[4];
#pragma unroll
    for (int p = 0; p < 4; ++p)
        b_src[p] = B + (size_t)(p * 8 + b_k) * N + bn + b_n;
    int aoff[4], boff[4];
#pragma unroll
    for (int mi = 0; mi < 4; ++mi) aoff[mi] = (wr + mi * 16 + l15) * LDT + lk8;
#pragma unroll
    for (int ni = 0; ni < 4; ++ni) boff[ni] = (wc + ni * 16 + l15) * LDT + lk8;

    f32x4 accM[4][4];
    f32x4 accR[4][4];
#pragma unroll
    for (int i = 0; i < 4; ++i)
#pragma unroll
        for (int j = 0; j < 4; ++j) {
            accM[i][j] = (f32x4){0.f, 0.f, 0.f, 0.f};
            accR[i][j] = (f32x4){0.f, 0.f, 0.f, 0.f};
        }

    float4 avr[4], bvr[4];
#pragma unroll
    for (int p = 0; p < 4; ++p) avr[p] = *(const float4*)(a_src[p]);
#pragma unroll
    for (int p = 0; p < 4; ++p)
        bvr[p] = bok ? *(const float4*)(b_src[p]) : make_float4(0.f, 0.f, 0.f, 0.f);

    for (int k0 = 0; k0 < K; k0 += 32) {
        __syncthreads();
#pragma unroll
        for (int p = 0; p < 4; ++p) {
            unsigned w0a, w1a, w0b, w1b;
            tsplit2_pair(avr[p].x, avr[p].y, w0a, w1a);
            tsplit2_pair(avr[p].z, avr[p].w, w0b, w1b);
            *(uint2*)&as[a_soff[p]]      = make_uint2(w0a, w0b);
            *(uint2*)&as[PT + a_soff[p]] = make_uint2(w1a, w1b);
        }
#pragma unroll
        for (int p = 0; p < 4; ++p)
            *(float4*)&bsrc[(p * 8 + b_k) * 128 + b_n] = bvr[p];

        int kn = k0 + 32;
        if (kn < K) {
#pragma unroll
            for (int p = 0; p < 4; ++p) avr[p] = *(const float4*)(a_src[p] + kn);
#pragma unroll
            for (int p = 0; p < 4; ++p)
                bvr[p] = bok ? *(const float4*)(b_src[p] + (size_t)kn * N)
                             : make_float4(0.f, 0.f, 0.f, 0.f);
        }
        __syncthreads();

#pragma unroll
        for (int q = 0; q < 4; ++q) {
            int kq = tkh + q * 4;
            float f0 = bsrc[(kq + 0) * 128 + tn];
            float f1 = bsrc[(kq + 1) * 128 + tn];
            float f2 = bsrc[(kq + 2) * 128 + tn];
            float f3 = bsrc[(kq + 3) * 128 + tn];
            unsigned w0a, w1a, w0b, w1b;
            tsplit2_pair(f0, f1, w0a, w1a);
            tsplit2_pair(f2, f3, w0b, w1b);
            int off = tn * LDT + kq;
            *(uint2*)&bs[off]      = make_uint2(w0a, w0b);
            *(uint2*)&bs[PT + off] = make_uint2(w1a, w1b);
        }
        __syncthreads();

        bf16x8 af[2][4];
#pragma unroll
        for (int p = 0; p < 2; ++p)
#pragma unroll
            for (int mi = 0; mi < 4; ++mi)
                af[p][mi] = *(const bf16x8*)&as[p * PT + aoff[mi]];

#pragma unroll
        for (int q = 0; q < 2; ++q) {
            bf16x8 bf[4];
#pragma unroll
            for (int ni = 0; ni < 4; ++ni)
                bf[ni] = *(const bf16x8*)&bs[q * PT + boff[ni]];
#pragma unroll
            for (int p = 0; p < 2; ++p) {
                if (p + q > 1) continue;
                if (p == 0 && q == 0) {
#pragma unroll
                    for (int mi = 0; mi < 4; ++mi)
#pragma unroll
                        for (int ni = 0; ni < 4; ++ni)
                            accM[mi][ni] = __builtin_amdgcn_mfma_f32_16x16x32_bf16(
                                af[0][mi], bf[ni], accM[mi][ni], 0, 0, 0);
                } else {
#pragma unroll
                    for (int mi = 0; mi < 4; ++mi)
#pragma unroll
                        for (int ni = 0; ni < 4; ++ni)
                            accR[mi][ni] = __builtin_amdgcn_mfma_f32_16x16x32_bf16(
                                af[p][mi], bf[ni], accR[mi][ni], 0, 0, 0);
                }
            }
        }
    }

    const int rsub = (lane >> 4) * 4;
#pragma unroll
    for (int mi = 0; mi < 4; ++mi) {
        int row0 = bm + wr + mi * 16 + rsub;
#pragma unroll
        for (int ni = 0; ni < 4; ++ni) {
            int col = bn + wc + ni * 16 + l15;
            if (col < N) {
                float bb = bias[col];
#pragma unroll
                for (int r = 0; r < 4; ++r) {
                    float s = accR[mi][ni][r] + accM[mi][ni][r];
                    C[(size_t)(row0 + r) * N + col] = fmaxf(s + bb, 0.f);
                }
            }
        }
    }
}

// ---- k-winner (exact top-512, radix on fp32 bits, jax leftmost ties) -------
__global__ __launch_bounds__(256)
void kwinner_stripes(float* h2, const float* bscores)
{
    const int row = blockIdx.x;
    const int tid = threadIdx.x;
    float* rowp = h2 + (size_t)row * DDIM;

    __shared__ float  mv[DDIM];
    __shared__ int    ired[256];
    __shared__ double dred[256];
    __shared__ int    warr[4];
    __shared__ double ssum[128];
    __shared__ float  smk[128];

#pragma unroll
    for (int i = 0; i < 32; ++i) {
        int j = tid + i * 256;
        mv[j] = expf(0.0f - bscores[j]) * rowp[j];   // BETA=1, GAMMA=0
    }
    __syncthreads();

    unsigned t = 0;
    for (int bit = 30; bit >= 0; --bit) {
        unsigned cand = t | (1u << bit);
        int cnt = 0;
#pragma unroll
        for (int i = 0; i < 32; ++i)
            cnt += (__float_as_uint(mv[tid + i * 256]) >= cand) ? 1 : 0;
        for (int off = 32; off; off >>= 1) cnt += __shfl_down(cnt, off);
        if ((tid & 63) == 0) warr[tid >> 6] = cnt;
        __syncthreads();
        int tot = warr[0] + warr[1] + warr[2] + warr[3];
        __syncthreads();
        if (tot >= KNEUR) t = cand;
    }
    {
        int cnt = 0;
#pragma unroll
        for (int i = 0; i < 32; ++i)
            cnt += (__float_as_uint(mv[tid + i * 256]) > t) ? 1 : 0;
        for (int off = 32; off; off >>= 1) cnt += __shfl_down(cnt, off);
        if ((tid & 63) == 0) warr[tid >> 6] = cnt;
        __syncthreads();
    }
    const int need_eq = KNEUR - (warr[0] + warr[1] + warr[2] + warr[3]);
    __syncthreads();

    const int base = tid * 32;
    int myeq = 0;
#pragma unroll
    for (int i = 0; i < 32; ++i)
        myeq += (__float_as_uint(mv[base + i]) == t) ? 1 : 0;
    int val = myeq;
    ired[tid] = val;
    __syncthreads();
    for (int s = 1; s < 256; s <<= 1) {
        int add = (tid >= s) ? ired[tid - s] : 0;
        __syncthreads();
        val += add;
        ired[tid] = val;
        __syncthreads();
    }
    const int before = val - myeq;

    double partial = 0.0;
    int eqseen = 0;
#pragma unroll
    for (int i = 0; i < 32; ++i) {
        int j = base + i;
        float m = mv[j];
        unsigned u = __float_as_uint(m);
        bool sel = (u > t) || (u == t && (before + eqseen) < need_eq);
        if (u == t) ++eqseen;
        float code = sel ? m * rowp[j] : 0.f;
        mv[j] = code;
        partial += (double)code;
    }
    dred[tid] = partial;
    __syncthreads();
    if (tid < 128) ssum[tid] = dred[2 * tid] + dred[2 * tid + 1];
    __syncthreads();

    if (tid < 128) {
        double v = ssum[tid];
        int rank = 0;
        for (int j = 0; j < 128; ++j) {
            double w = ssum[j];
            rank += (w > v) ? 1 : 0;
            rank += (w == v && j < tid) ? 1 : 0;
        }
        smk[tid] = (rank < KSTR) ? 1.f : 0.f;
    }
    __syncthreads();

#pragma unroll
    for (int i = 0; i < 32; ++i) {
        int j = tid + i * 256;
        rowp[j] = mv[j] * smk[j >> 6];
    }
}

// ---------------------------------------------------------------------------
extern "C" void kernel_launch(void* const* d_in, const int* in_sizes, int n_in,
                              void* d_out, int out_size, void* d_ws, size_t ws_size,
                              hipStream_t stream)
{
    float* out = (float*)d_out;
    const unsigned long long on = (unsigned long long)out_size;

    if (n_in != 10) {
        Net_49976239456390_kernel<<<1024, 256, 0, stream>>>(out, on, 55.f);
        return;
    }
    if (in_sizes[0] != BDIM * XDIM || in_sizes[3] != IDIM * DDIM || in_sizes[9] != DDIM) {
        Net_49976239456390_kernel<<<1024, 256, 0, stream>>>(out, on, 66.f);
        return;
    }
    const size_t need = (size_t)BDIM * IDIM * 4 + (size_t)BDIM * DDIM * 4;
    if (need > ws_size) {
        Net_49976239456390_kernel<<<1024, 256, 0, stream>>>(out, on, 99.f);
        return;
    }

    Net_49976239456390_kernel<<<1024, 256, 0, stream>>>(out, on, 7.f);

    const float* x   = (const float*)d_in[0];
    const float* W1  = (const float*)d_in[1];
    const float* b1  = (const float*)d_in[2];
    const float* W2  = (const float*)d_in[3];
    const float* b2  = (const float*)d_in[4];
    const float* W3  = (const float*)d_in[5];
    const float* b3  = (const float*)d_in[6];
    const float* W4  = (const float*)d_in[7];
    const float* b4  = (const float*)d_in[8];
    const float* bsc = (const float*)d_in[9];

    float* h1 = (float*)d_ws;                     // [B][I], reused as h3
    float* h2 = h1 + (size_t)BDIM * IDIM;         // [B][D], flat in place

    dim3 blk(256);
    // GEMM1: K=784 (guarded tail), 3-term split MFMA
    gemm_m3split<true><<<dim3(IDIM / 128, BDIM / 128), blk, 0, stream>>>(
        x, W1, b1, h1, IDIM, XDIM);
    // GEMM2: selection-critical, 3-term split MFMA (trunc splits)
    gemm_m3split<false><<<dim3(DDIM / 128, BDIM / 128), blk, 0, stream>>>(
        h1, W2, b2, h2, DDIM, IDIM);
    kwinner_stripes<<<dim3(BDIM), blk, 0, stream>>>(h2, bsc);
    gemm_v2split<<<dim3(IDIM / 128, BDIM / 128), blk, 0, stream>>>(
        h2, W3, b3, h1, IDIM, DDIM);
    gemm_v2split<<<dim3((XDIM + 127) / 128, BDIM / 128), blk, 0, stream>>>(
        h1, W4, b4, out, XDIM, IDIM);
}